// Round 10
// baseline (2062.755 us; speedup 1.0000x reference)
//
#include <hip/hip_runtime.h>
#include <hip/hip_bf16.h>
#include <math.h>

// Problem constants
#define BB   4
#define NN   1024
#define DD   768
#define HHH  12
#define LLL  12
#define FFD  3072
#define MMM  8
#define CCC  527
#define PDIM 256

typedef unsigned short u16;
typedef __attribute__((ext_vector_type(8))) short bf16x8;
typedef __attribute__((ext_vector_type(4))) float f32x4;

__device__ inline float b2f(u16 x) {
    union { float f; unsigned u; } c; c.u = ((unsigned)x) << 16; return c.f;
}
__device__ inline u16 f2b(float f) {
    __hip_bfloat16 h = __float2bfloat16(f);
    return *reinterpret_cast<u16*>(&h);
}

// exact-GELU via Abramowitz-Stegun 7.1.26 erf (max abs err 1.5e-7) — ~14 VALU ops
__device__ __forceinline__ float gelu_fast(float v) {
    const float x = v * 0.70710678118f;
    const float xa = fabsf(x);
    const float tt = 1.f / (1.f + 0.3275911f * xa);
    const float poly = tt * (0.254829592f + tt * (-0.284496736f + tt * (1.421413741f +
                       tt * (-1.453152027f + tt * 1.061405429f))));
    float er = 1.f - poly * __expf(-xa * xa);
    er = (x < 0.f) ? -er : er;
    return 0.5f * v * (1.f + er);
}

// async global->LDS 16B copy (LDS dest is wave-uniform base + lane*16)
__device__ __forceinline__ void gl_lds16(const u16* g, const u16* l) {
    __builtin_amdgcn_global_load_lds(
        (const __attribute__((address_space(1))) unsigned int*)(unsigned long long)g,
        (__attribute__((address_space(3))) unsigned int*)(unsigned)(unsigned long long)l,
        16, 0, 0);
}

// ---------------- key_pad normalizer: handles bool-as-bytes OR bool-as-int32 ----------------
__global__ void k_pad_norm(const void* __restrict__ p, unsigned char* __restrict__ out, int n) {
    __shared__ int isInt;
    const int t = threadIdx.x;  // single block, 1024 threads
    if (t == 0) isInt = 1;
    __syncthreads();
    const unsigned* up = (const unsigned*)p;
    for (int i = t; i < n / 4; i += 1024) {
        unsigned v = up[i];
        if (v > 1u) isInt = 0;  // benign race
    }
    __syncthreads();
    const int* ip = (const int*)p;
    const unsigned char* cp = (const unsigned char*)p;
    const int mode = isInt;
    for (int i = t; i < n; i += 1024)
        out[i] = mode ? (unsigned char)(ip[i] != 0) : (unsigned char)(cp[i] != 0);
}

// ---------------- weight transpose + f32->bf16 convert (coalesced stores) ----------------
// src: [z][K][N] f32 ; dst: [z][N][K] bf16. Tile: 64 k x 32 n.
__global__ __launch_bounds__(256) void k_transpose_cvt(
    const float* __restrict__ src, u16* __restrict__ dst,
    int K, int N, long srcLS, long dstLS)
{
    __shared__ float t[64][33];
    const float* s = src + (size_t)blockIdx.z * srcLS;
    u16* d = dst + (size_t)blockIdx.z * dstLS;
    const int n0 = blockIdx.x * 32, k0 = blockIdx.y * 64;
    const int tx = threadIdx.x & 31, ty = threadIdx.x >> 5;  // ty 0..7
    #pragma unroll
    for (int i = 0; i < 8; i++)
        t[ty * 8 + i][tx] = s[(size_t)(k0 + ty * 8 + i) * N + n0 + tx];
    __syncthreads();
    #pragma unroll
    for (int p = 0; p < 4; p++) {
        const int ny = p * 8 + ty;
        union { u16 h[2]; unsigned u; } o;
        o.h[0] = f2b(t[2 * tx][ny]);
        o.h[1] = f2b(t[2 * tx + 1][ny]);
        *(unsigned*)&d[(size_t)(n0 + ny) * K + k0 + 2 * tx] = o.u;
    }
}

// ---------------- plain f32 -> bf16 convert (vectorized) ----------------
__global__ __launch_bounds__(256) void k_cvt(const float* __restrict__ s, u16* __restrict__ d, int n4) {
    int i = blockIdx.x * 256 + threadIdx.x;
    if (i >= n4) return;
    float4 v = ((const float4*)s)[i];
    union { u16 h[4]; uint2 u; } o;
    o.h[0] = f2b(v.x); o.h[1] = f2b(v.y); o.h[2] = f2b(v.z); o.h[3] = f2b(v.w);
    ((uint2*)d)[i] = o.u;
}

// ---------------- pack qkv bias: [L][2304] = concat(bq, bkv) ----------------
__global__ __launch_bounds__(256) void k_bias_pack(const float* __restrict__ bq,
                                                   const float* __restrict__ bkv,
                                                   float* __restrict__ bqkv) {
    int i = blockIdx.x * 256 + threadIdx.x;
    if (i >= LLL * 2304) return;
    int l = i / 2304, c = i % 2304;
    bqkv[i] = (c < 768) ? bq[l * 768 + c] : bkv[l * 1536 + (c - 768)];
}

// ---------------- per-(b,qtile) and per-(b,m) contiguous j ranges ----------------
__global__ void k_ranges(const int* __restrict__ sid, int2* __restrict__ qr, int2* __restrict__ pr) {
    int b = blockIdx.x, t = threadIdx.x;
    const int* s = sid + b * NN;
    if (t < 16) {
        int lo_id = s[t * 64], hi_id = s[t * 64 + 63];
        int lo = 0, hi = NN;
        while (lo < hi) { int mid = (lo + hi) >> 1; if (s[mid] < lo_id) lo = mid + 1; else hi = mid; }
        int l2 = 0, h2 = NN;
        while (l2 < h2) { int mid = (l2 + h2) >> 1; if (s[mid] <= hi_id) l2 = mid + 1; else h2 = mid; }
        qr[b * 16 + t] = make_int2(lo, l2);
    }
    if (t < MMM) {
        int l2 = 0, h2 = NN;
        while (l2 < h2) { int mid = (l2 + h2) >> 1; if (s[mid] < t) l2 = mid + 1; else h2 = mid; }
        int l3 = 0, h3 = NN;
        while (l3 < h3) { int mid = (l3 + h3) >> 1; if (s[mid] <= t) l3 = mid + 1; else h3 = mid; }
        pr[b * MMM + t] = make_int2(l2, l3);
    }
}

// ---------------- LayerNorm: f32 in -> bf16 (or f32) out, row = 768 ----------------
__device__ inline void stv(u16* p, float v) { *p = f2b(v); }
__device__ inline void stv(float* p, float v) { *p = v; }

template <typename OT>
__global__ __launch_bounds__(256) void k_ln(const float* __restrict__ x,
                                            const float* __restrict__ g,
                                            const float* __restrict__ b,
                                            OT* __restrict__ out) {
    int row = blockIdx.x;
    const float* xr = x + (size_t)row * DD;
    int t = threadIdx.x;
    float v[3], s1 = 0.f, s2 = 0.f;
    #pragma unroll
    for (int i = 0; i < 3; i++) { v[i] = xr[t + i * 256]; s1 += v[i]; s2 += v[i] * v[i]; }
    #pragma unroll
    for (int o = 32; o; o >>= 1) { s1 += __shfl_xor(s1, o); s2 += __shfl_xor(s2, o); }
    __shared__ float a1[4], a2[4];
    int w = t >> 6;
    if ((t & 63) == 0) { a1[w] = s1; a2[w] = s2; }
    __syncthreads();
    s1 = a1[0] + a1[1] + a1[2] + a1[3];
    s2 = a2[0] + a2[1] + a2[2] + a2[3];
    float mean = s1 * (1.f / DD);
    float var = s2 * (1.f / DD) - mean * mean;
    float rstd = rsqrtf(fmaxf(var, 0.f) + 1e-6f);
    #pragma unroll
    for (int i = 0; i < 3; i++) {
        int c = t + i * 256;
        stv(&out[(size_t)row * DD + c], (v[i] - mean) * rstd * g[c] + b[c]);
    }
}

// ---------------- bf16 MFMA GEMM, BMx128 tile, 2-deep counted-vmcnt pipeline ----------------
// T3+T4 (3 LDS buffers, 2 tiles in flight, counted s_waitcnt vmcnt) + T1 XCD swizzle + T5 setprio.
// EPI: 0 = bf16 out, 1 = f32 out + residual (in place), 2 = GELU bf16 out,
//      3 = f32 out, 5 = f32 out + positional embeds (fused embed+posadd)
// BM: 128 (waves 2x2 of 64x64, L=4) or 64 (waves 1x4 of 64x32, L=3)
template <int EPI, int BM>
__global__ __launch_bounds__(256) void k_gemm(
    const u16* __restrict__ A, int lda,
    const u16* __restrict__ Bt, int ldb,
    const float* __restrict__ bias,
    float* __restrict__ Cf, u16* __restrict__ Cb,
    const float* __restrict__ resid,
    int ldc, int K,
    const int* __restrict__ fidx = nullptr, const int* __restrict__ tidx = nullptr,
    const float* __restrict__ pf = nullptr, const float* __restrict__ pt = nullptr)
{
    constexpr int NR  = (BM == 128) ? 4 : 2;     // B-frags per wave
    constexpr int ASZ = BM * 32;                 // u16 per A buffer
    constexpr int BSZ = 128 * 32;
    __shared__ __align__(16) u16 As[3][ASZ];
    __shared__ __align__(16) u16 Bs[3][BSZ];
    const int gx = gridDim.x;
    const int nwg = gx * gridDim.y;
    int bid = blockIdx.y * gx + blockIdx.x;
    if ((nwg & 7) == 0) bid = (bid & 7) * (nwg >> 3) + (bid >> 3);
    const int row0 = (bid / gx) * BM, col0 = (bid % gx) * 128;
    const int t = threadIdx.x;
    const int w = t >> 6, lane = t & 63;
    const int wr = (BM == 128) ? (w >> 1) * 64 : 0;
    const int wc = (BM == 128) ? (w & 1) * 64 : w * 32;
    const int fr = lane & 15, fg = lane >> 4;
    const int srow = t >> 2, sseg = (t & 3) * 8;     // sseg in u16 elems
    const u16* Ap = A + (size_t)(row0 + srow) * lda + sseg;
    const u16* Bp = Bt + (size_t)(col0 + srow) * ldb + sseg;
    const size_t lstep = (size_t)64 * lda, bstep = (size_t)64 * ldb;

    auto stage = [&](int buf, int k0) {
        #pragma unroll
        for (int i = 0; i < BM / 64; i++)
            gl_lds16(Ap + i * lstep + k0, &As[buf][i * 2048 + t * 8]);
        #pragma unroll
        for (int i = 0; i < 2; i++)
            gl_lds16(Bp + i * bstep + k0, &Bs[buf][i * 2048 + t * 8]);
    };

    f32x4 acc[4][NR];
    #pragma unroll
    for (int m = 0; m < 4; m++)
        #pragma unroll
        for (int n = 0; n < NR; n++) acc[m][n] = (f32x4){0.f, 0.f, 0.f, 0.f};

    const int nt = K >> 5;
    stage(0, 0);
    stage(1, 32);

    for (int kt = 0; kt < nt; ++kt) {
        if (kt + 1 < nt) {
            if constexpr (BM == 128) asm volatile("s_waitcnt vmcnt(4)" ::: "memory");
            else                     asm volatile("s_waitcnt vmcnt(3)" ::: "memory");
        } else {
            asm volatile("s_waitcnt vmcnt(0)" ::: "memory");
        }
        __builtin_amdgcn_s_barrier();
        __builtin_amdgcn_sched_barrier(0);
        if (kt + 2 < nt) stage((kt + 2) % 3, (kt + 2) * 32);
        const int cur = kt % 3;
        bf16x8 af[4], bfr[NR];
        #pragma unroll
        for (int m = 0; m < 4; m++) af[m] = *(const bf16x8*)&As[cur][(wr + m * 16 + fr) * 32 + fg * 8];
        #pragma unroll
        for (int n = 0; n < NR; n++) bfr[n] = *(const bf16x8*)&Bs[cur][(wc + n * 16 + fr) * 32 + fg * 8];
        __builtin_amdgcn_s_setprio(1);
        #pragma unroll
        for (int m = 0; m < 4; m++)
            #pragma unroll
            for (int n = 0; n < NR; n++)
                acc[m][n] = __builtin_amdgcn_mfma_f32_16x16x32_bf16(af[m], bfr[n], acc[m][n], 0, 0, 0);
        __builtin_amdgcn_s_setprio(0);
    }
    #pragma unroll
    for (int m = 0; m < 4; m++) {
        #pragma unroll
        for (int n = 0; n < NR; n++) {
            const int col = col0 + wc + n * 16 + fr;
            const float bb = bias[col];
            #pragma unroll
            for (int r = 0; r < 4; r++) {
                const size_t row = row0 + wr + m * 16 + fg * 4 + r;
                float v = acc[m][n][r] + bb;
                if (EPI == 0) {
                    Cb[row * ldc + col] = f2b(v);
                } else if (EPI == 1) {
                    Cf[row * ldc + col] = v + resid[row * ldc + col];
                } else if (EPI == 2) {
                    Cb[row * ldc + col] = f2b(gelu_fast(v));
                } else if (EPI == 3) {
                    Cf[row * ldc + col] = v;
                } else if (EPI == 5) {
                    const int fi = fidx[row], ti = tidx[row];
                    Cf[row * ldc + col] = v + pf[(size_t)fi * DD + col] + pt[(size_t)ti * DD + col];
                }
            }
        }
    }
}

// ---------------- block-diagonal flash attention (no 1/sqrt(d) scaling) ----------------
// qkv: [B*N][2304] bf16 (q | k | v); out: [B*N][768] bf16
// T14 async-stage + V^T swizzle + T5 setprio around MFMA clusters.
__global__ __launch_bounds__(256) void k_attn(
    const u16* __restrict__ qkv,
    const int* __restrict__ sid, const unsigned char* __restrict__ pad,
    const int2* __restrict__ qr,
    u16* __restrict__ outb)
{
    __shared__ __align__(16) u16 Qs[64][72];
    __shared__ __align__(16) u16 Ks[64][72];
    __shared__ __align__(16) u16 VtL[64 * 72 + 32];  // VOFF(d) = d*72 + ((d>>4)<<3)
    __shared__ __align__(16) u16 Ps[4][16][72];      // per-wave P tile
    __shared__ int sidq[64];
    __shared__ int sidj[64];
    __shared__ int padj[64];
    const int b = blockIdx.z, h = blockIdx.y, qt = blockIdx.x;
    const int i0 = qt * 64;
    const int t = threadIdx.x, w = t >> 6, lane = t & 63;
    const int fr = lane & 15, fg = lane >> 4;
    const int srow = t >> 2, sseg = (t & 3) * 16;
    const size_t tokbase = (size_t)b * NN;
    const u16* qbase = qkv + (tokbase + i0) * 2304 + h * 64;
    *(uint4*)&Qs[srow][sseg]     = *(const uint4*)(qbase + (size_t)srow * 2304 + sseg);
    *(uint4*)&Qs[srow][sseg + 8] = *(const uint4*)(qbase + (size_t)srow * 2304 + sseg + 8);
    if (t < 64) sidq[t] = sid[tokbase + i0 + t];
    __syncthreads();
    bf16x8 qf0 = *(const bf16x8*)&Qs[w * 16 + fr][fg * 8];
    bf16x8 qf1 = *(const bf16x8*)&Qs[w * 16 + fr][32 + fg * 8];
    const int myrow = w * 16 + fg * 4;
    float m_run[4], l_run[4];
    f32x4 oacc[4];
    #pragma unroll
    for (int r = 0; r < 4; r++) { m_run[r] = -1e30f; l_run[r] = 0.f; }
    #pragma unroll
    for (int n = 0; n < 4; n++) oacc[n] = (f32x4){0.f, 0.f, 0.f, 0.f};
    const int2 rg = qr[b * 16 + qt];
    const u16* kbase = qkv + tokbase * 2304 + 768 + h * 64;
    const u16* vbase = qkv + tokbase * 2304 + 1536 + h * 64;

    // prologue: load first tile into registers
    uint4 rk0, rk1, rv0, rv1;
    int rsid = 0, rpad = 0;
    const int jstart = rg.x & ~63;
    {
        const size_t ro = (size_t)(jstart + srow) * 2304;
        rk0 = *(const uint4*)(kbase + ro + sseg);
        rk1 = *(const uint4*)(kbase + ro + sseg + 8);
        rv0 = *(const uint4*)(vbase + ro + sseg);
        rv1 = *(const uint4*)(vbase + ro + sseg + 8);
        if (t < 64) { rsid = sid[tokbase + jstart + t]; rpad = pad[tokbase + jstart + t]; }
    }

    for (int j0 = jstart; j0 < rg.y; j0 += 64) {
        __syncthreads();           // prior compute done; LDS writable
        *(uint4*)&Ks[srow][sseg]     = rk0;
        *(uint4*)&Ks[srow][sseg + 8] = rk1;
        {
            u16 tmp[16];
            *(uint4*)&tmp[0] = rv0;
            *(uint4*)&tmp[8] = rv1;
            const int goff = (sseg >> 4) << 3;   // swizzle offset, constant per thread
            #pragma unroll
            for (int e = 0; e < 16; e++)
                VtL[(sseg + e) * 72 + goff + srow] = tmp[e];
        }
        if (t < 64) { sidj[t] = rsid; padj[t] = rpad; }
        __syncthreads();           // tile resident
        if (j0 + 64 < rg.y) {      // prefetch next tile into regs (in flight during compute)
            const size_t ro = (size_t)(j0 + 64 + srow) * 2304;
            rk0 = *(const uint4*)(kbase + ro + sseg);
            rk1 = *(const uint4*)(kbase + ro + sseg + 8);
            rv0 = *(const uint4*)(vbase + ro + sseg);
            rv1 = *(const uint4*)(vbase + ro + sseg + 8);
            if (t < 64) { rsid = sid[tokbase + j0 + 64 + t]; rpad = pad[tokbase + j0 + 64 + t]; }
        }
        // S = Q K^T  (16 q-rows per wave x 64 j)
        f32x4 s[4];
        __builtin_amdgcn_s_setprio(1);
        #pragma unroll
        for (int nj = 0; nj < 4; nj++) {
            bf16x8 kf0 = *(const bf16x8*)&Ks[nj * 16 + fr][fg * 8];
            bf16x8 kf1 = *(const bf16x8*)&Ks[nj * 16 + fr][32 + fg * 8];
            f32x4 a = (f32x4){0.f, 0.f, 0.f, 0.f};
            a = __builtin_amdgcn_mfma_f32_16x16x32_bf16(qf0, kf0, a, 0, 0, 0);
            a = __builtin_amdgcn_mfma_f32_16x16x32_bf16(qf1, kf1, a, 0, 0, 0);
            s[nj] = a;
        }
        __builtin_amdgcn_s_setprio(0);
        // mask
        #pragma unroll
        for (int nj = 0; nj < 4; nj++) {
            const int jj = nj * 16 + fr;
            const int sj = sidj[jj];
            const int pd = padj[jj];
            #pragma unroll
            for (int r = 0; r < 4; r++) {
                const bool ok = pd && (sj == sidq[myrow + r]);
                s[nj][r] = ok ? s[nj][r] : -3e38f;
            }
        }
        // online softmax (rows live on 16-lane groups)
        float mnew[4], scale[4];
        #pragma unroll
        for (int r = 0; r < 4; r++) {
            float mx = fmaxf(fmaxf(s[0][r], s[1][r]), fmaxf(s[2][r], s[3][r]));
            #pragma unroll
            for (int o = 1; o < 16; o <<= 1) mx = fmaxf(mx, __shfl_xor(mx, o));
            mnew[r] = fmaxf(m_run[r], mx);
            scale[r] = __expf(m_run[r] - mnew[r]);
            m_run[r] = mnew[r];
        }
        #pragma unroll
        for (int r = 0; r < 4; r++) {
            float rs = 0.f;
            #pragma unroll
            for (int nj = 0; nj < 4; nj++) {
                float pv = __expf(s[nj][r] - mnew[r]);
                rs += pv;
                Ps[w][fg * 4 + r][nj * 16 + fr] = f2b(pv);
            }
            #pragma unroll
            for (int o = 1; o < 16; o <<= 1) rs += __shfl_xor(rs, o);
            l_run[r] = l_run[r] * scale[r] + rs;
        }
        #pragma unroll
        for (int n = 0; n < 4; n++)
            #pragma unroll
            for (int r = 0; r < 4; r++) oacc[n][r] *= scale[r];
        // O += P V   (P via per-wave LDS relayout; same-wave DS ordering is program order)
        bf16x8 pa0 = *(const bf16x8*)&Ps[w][fr][fg * 8];
        bf16x8 pa1 = *(const bf16x8*)&Ps[w][fr][32 + fg * 8];
        __builtin_amdgcn_s_setprio(1);
        #pragma unroll
        for (int nd = 0; nd < 4; nd++) {
            bf16x8 vf0 = *(const bf16x8*)&VtL[(nd * 16 + fr) * 72 + nd * 8 + fg * 8];
            bf16x8 vf1 = *(const bf16x8*)&VtL[(nd * 16 + fr) * 72 + nd * 8 + 32 + fg * 8];
            oacc[nd] = __builtin_amdgcn_mfma_f32_16x16x32_bf16(pa0, vf0, oacc[nd], 0, 0, 0);
            oacc[nd] = __builtin_amdgcn_mfma_f32_16x16x32_bf16(pa1, vf1, oacc[nd], 0, 0, 0);
        }
        __builtin_amdgcn_s_setprio(0);
    }
    float inv[4];
    #pragma unroll
    for (int r = 0; r < 4; r++) inv[r] = 1.f / l_run[r];
    #pragma unroll
    for (int nd = 0; nd < 4; nd++)
        #pragma unroll
        for (int r = 0; r < 4; r++)
            outb[(tokbase + i0 + myrow + r) * DD + h * 64 + nd * 16 + fr] = f2b(oacc[nd][r] * inv[r]);
}

// ---------------- pool query vector: qv[c] = pool_q . pool_Wq[:,c] + pool_bq[c] ----------------
__global__ __launch_bounds__(64) void k_qvec(const float* __restrict__ pq, const float* __restrict__ Wq,
                                             const float* __restrict__ bq, float* __restrict__ qv) {
    int c = blockIdx.x;
    int l = threadIdx.x;
    float s = 0.f;
    #pragma unroll
    for (int d = l; d < DD; d += 64) s += pq[d] * Wq[(size_t)d * DD + c];
    #pragma unroll
    for (int o = 32; o; o >>= 1) s += __shfl_xor(s, o);
    if (l == 0) qv[c] = s + bq[c];
}

// ---------------- attention pooling: one block per (b, m, h) ----------------
__global__ __launch_bounds__(256) void k_pool_attn(
    const float* __restrict__ qv, const u16* __restrict__ kv,
    const unsigned char* __restrict__ pad, const int2* __restrict__ pr,
    float* __restrict__ outp)
{
    const int idx = blockIdx.x;                 // ((b*8+m)*12+h)
    const int h = idx % HHH, bm = idx / HHH;
    const int b = bm >> 3, m = bm & 7;
    const int2 rg = pr[b * MMM + m];
    const int lo = rg.x, cnt = rg.y - rg.x;
    __shared__ float sc[NN];
    __shared__ float qsh[64];
    __shared__ float rbuf[4];
    __shared__ float vacc[4][64];
    if (threadIdx.x < 64) qsh[threadIdx.x] = qv[h * 64 + threadIdx.x];
    __syncthreads();
    // scores (vectorized 16B K loads)
    for (int j = threadIdx.x; j < cnt; j += 256) {
        const u16* krow = kv + (size_t)(b * NN + lo + j) * 1536 + h * 64;
        float s = 0.f;
        #pragma unroll
        for (int dv = 0; dv < 8; dv++) {
            bf16x8 k8 = *(const bf16x8*)(krow + dv * 8);
            #pragma unroll
            for (int e = 0; e < 8; e++) s += qsh[dv * 8 + e] * b2f((u16)k8[e]);
        }
        sc[j] = pad[b * NN + lo + j] ? s : -3e38f;
    }
    __syncthreads();
    float mx = -3e38f;
    for (int j = threadIdx.x; j < cnt; j += 256) mx = fmaxf(mx, sc[j]);
    #pragma unroll
    for (int o = 32; o; o >>= 1) mx = fmaxf(mx, __shfl_xor(mx, o));
    if ((threadIdx.x & 63) == 0) rbuf[threadIdx.x >> 6] = mx;
    __syncthreads();
    mx = fmaxf(fmaxf(rbuf[0], rbuf[1]), fmaxf(rbuf[2], rbuf[3]));
    __syncthreads();
    float sm = 0.f;
    for (int j = threadIdx.x; j < cnt; j += 256) { float p = __expf(sc[j] - mx); sc[j] = p; sm += p; }
    #pragma unroll
    for (int o = 32; o; o >>= 1) sm += __shfl_xor(sm, o);
    if ((threadIdx.x & 63) == 0) rbuf[threadIdx.x >> 6] = sm;
    __syncthreads();
    sm = rbuf[0] + rbuf[1] + rbuf[2] + rbuf[3];
    const float inv = 1.f / sm;
    {
        const int d = threadIdx.x & 63, g = threadIdx.x >> 6;
        float acc = 0.f;
        for (int j = g; j < cnt; j += 4)
            acc += sc[j] * b2f(kv[(size_t)(b * NN + lo + j) * 1536 + 768 + h * 64 + d]);
        vacc[g][d] = acc;
        __syncthreads();
        if (g == 0)
            outp[(size_t)(b * MMM + m) * DD + h * 64 + d] =
                (vacc[0][d] + vacc[1][d] + vacc[2][d] + vacc[3][d]) * inv;
    }
}

// ---------------- small f32 GEMM: out[32][N] = A[32][768] @ W[768][N] + bias ----------------
__global__ __launch_bounds__(256) void k_small_mm(const float* __restrict__ A, const float* __restrict__ W,
                                                  const float* __restrict__ bias, float* __restrict__ out,
                                                  int N, int Kd) {
    const int row = blockIdx.y;
    const int cl = threadIdx.x & 63, kg = threadIdx.x >> 6;
    const int c = blockIdx.x * 64 + cl;
    const int cload = (c < N) ? c : (N - 1);
    __shared__ float As[DD];
    __shared__ float red[4][64];
    for (int d = threadIdx.x; d < Kd; d += 256) As[d] = A[(size_t)row * Kd + d];
    __syncthreads();
    const int kper = Kd >> 2;
    const int kbase = kg * kper;
    float s = 0.f;
    const float* w = W + (size_t)kbase * N + cload;
    #pragma unroll 4
    for (int i = 0; i < kper; i++) s += As[kbase + i] * w[(size_t)i * N];
    red[kg][cl] = s;
    __syncthreads();
    if (kg == 0 && c < N)
        out[(size_t)row * N + c] = red[0][cl] + red[1][cl] + red[2][cl] + red[3][cl] + bias[c];
}

// =======================================================================
extern "C" void kernel_launch(void* const* d_in, const int* in_sizes, int n_in,
                              void* d_out, int out_size, void* d_ws, size_t ws_size,
                              hipStream_t stream) {
    const float* patches   = (const float*)d_in[0];
    const int*   sample_ids= (const int*)d_in[1];
    const void*  key_pad_raw = (const void*)d_in[2];   // bool: byte OR int32 — normalized below
    const int*   freq_idx  = (const int*)d_in[3];
    const int*   time_idx  = (const int*)d_in[4];
    const float* patch_W   = (const float*)d_in[5];
    const float* patch_b   = (const float*)d_in[6];
    const float* pos_f     = (const float*)d_in[7];
    const float* pos_t     = (const float*)d_in[8];
    const float* ln1_g     = (const float*)d_in[9];
    const float* ln1_b     = (const float*)d_in[10];
    const float* Wq        = (const float*)d_in[11];
    const float* bq        = (const float*)d_in[12];
    const float* Wkv       = (const float*)d_in[13];
    const float* bkv       = (const float*)d_in[14];
    const float* Wo        = (const float*)d_in[15];
    const float* bo        = (const float*)d_in[16];
    const float* ln2_g     = (const float*)d_in[17];
    const float* ln2_b     = (const float*)d_in[18];
    const float* W1        = (const float*)d_in[19];
    const float* b1        = (const float*)d_in[20];
    const float* W2        = (const float*)d_in[21];
    const float* b2        = (const float*)d_in[22];
    const float* norm_g    = (const float*)d_in[23];
    const float* norm_b    = (const float*)d_in[24];
    const float* pool_q    = (const float*)d_in[25];
    const float* pool_Wq   = (const float*)d_in[26];
    const float* pool_bq   = (const float*)d_in[27];
    const float* pool_Wkv  = (const float*)d_in[28];
    const float* pool_bkv  = (const float*)d_in[29];
    const float* pool_Wo   = (const float*)d_in[30];
    const float* pool_bo   = (const float*)d_in[31];
    const float* mln_g     = (const float*)d_in[32];
    const float* mln_b     = (const float*)d_in[33];
    const float* head_W    = (const float*)d_in[34];
    const float* head_b    = (const float*)d_in[35];
    float* outp = (float*)d_out;
    (void)in_sizes; (void)n_in; (void)out_size; (void)ws_size;

    char* ws = (char*)d_ws;
    size_t off = 0;
    auto alloc = [&](size_t bytes) -> void* {
        void* p = (void*)(ws + off);
        off += (bytes + 255) & ~(size_t)255;
        return p;
    };
    // persistent: bf16 transposed weights (~165 MB)
    u16* WqkvT    = (u16*)alloc((size_t)LLL * 2304 * 768 * 2);
    u16* WoT      = (u16*)alloc((size_t)LLL * 768 * 768 * 2);
    u16* W1T      = (u16*)alloc((size_t)LLL * 3072 * 768 * 2);
    u16* W2T      = (u16*)alloc((size_t)LLL * 768 * 3072 * 2);
    u16* patchWT  = (u16*)alloc((size_t)768 * 256 * 2);
    u16* poolWkvT = (u16*)alloc((size_t)1536 * 768 * 2);
    float* bqkv   = (float*)alloc((size_t)LLL * 2304 * 4);
    unsigned char* pad_u8 = (unsigned char*)alloc(BB * NN);
    // activations (~66 MB, with aliasing)
    float* x      = (float*)alloc((size_t)4096 * 768 * 4);
    u16* hbuf     = (u16*)alloc((size_t)4096 * 768 * 2);
    u16* qkvb     = (u16*)alloc((size_t)4096 * 2304 * 2);
    u16* attno    = (u16*)alloc((size_t)4096 * 768 * 2);
    u16* mid      = (u16*)alloc((size_t)4096 * 3072 * 2);
    u16* patch_bf = mid;     // alias: patch_bf (4096x256) dead before first W1 GEMM
    u16* xn       = attno;   // alias: xn written after last attno read
    u16* poolkv   = qkvb;    // alias: poolkv written after last qkvb read
    float* qvec   = (float*)alloc(768 * 4);
    float* pooled_pre = (float*)alloc(32 * 768 * 4);
    float* pooled2    = (float*)alloc(32 * 768 * 4);
    float* mlnout     = (float*)alloc(32 * 768 * 4);
    int2* qr = (int2*)alloc(4 * 16 * sizeof(int2));
    int2* pr = (int2*)alloc(4 * 8 * sizeof(int2));

    // ---- input prep ----
    k_pad_norm<<<1, 1024, 0, stream>>>(key_pad_raw, pad_u8, BB * NN);
    k_transpose_cvt<<<dim3(24, 12, LLL), 256, 0, stream>>>(Wq, WqkvT, 768, 768, (long)768 * 768, (long)2304 * 768);
    k_transpose_cvt<<<dim3(48, 12, LLL), 256, 0, stream>>>(Wkv, WqkvT + (size_t)768 * 768, 768, 1536, (long)768 * 1536, (long)2304 * 768);
    k_transpose_cvt<<<dim3(24, 12, LLL), 256, 0, stream>>>(Wo, WoT, 768, 768, (long)768 * 768, (long)768 * 768);
    k_transpose_cvt<<<dim3(96, 12, LLL), 256, 0, stream>>>(W1, W1T, 768, 3072, (long)768 * 3072, (long)3072 * 768);
    k_transpose_cvt<<<dim3(24, 48, LLL), 256, 0, stream>>>(W2, W2T, 3072, 768, (long)3072 * 768, (long)768 * 3072);
    k_transpose_cvt<<<dim3(24, 4, 1), 256, 0, stream>>>(patch_W, patchWT, 256, 768, 0, 0);
    k_transpose_cvt<<<dim3(48, 12, 1), 256, 0, stream>>>(pool_Wkv, poolWkvT, 768, 1536, 0, 0);
    k_cvt<<<1024, 256, 0, stream>>>(patches, patch_bf, 4096 * 256 / 4);
    k_bias_pack<<<(LLL * 2304 + 255) / 256, 256, 0, stream>>>(bq, bkv, bqkv);
    k_ranges<<<4, 64, 0, stream>>>(sample_ids, qr, pr);

    // ---- embed + positional (fused epilogue) ----
    k_gemm<5, 64><<<dim3(6, 64), 256, 0, stream>>>(patch_bf, 256, patchWT, 256, patch_b, x, nullptr, nullptr,
                                                   768, 256, freq_idx, time_idx, pos_f, pos_t);

    // ---- transformer layers ----
    for (int l = 0; l < LLL; l++) {
        k_ln<u16><<<4096, 256, 0, stream>>>(x, ln1_g + l * 768, ln1_b + l * 768, hbuf);
        k_gemm<0, 128><<<dim3(18, 32), 256, 0, stream>>>(hbuf, 768, WqkvT + (size_t)l * 2304 * 768, 768,
                                                         bqkv + l * 2304, nullptr, qkvb, nullptr, 2304, 768);
        k_attn<<<dim3(16, 12, 4), 256, 0, stream>>>(qkvb, sample_ids, pad_u8, qr, attno);
        k_gemm<1, 64><<<dim3(6, 64), 256, 0, stream>>>(attno, 768, WoT + (size_t)l * 768 * 768, 768,
                                                       bo + l * 768, x, nullptr, x, 768, 768);
        k_ln<u16><<<4096, 256, 0, stream>>>(x, ln2_g + l * 768, ln2_b + l * 768, hbuf);
        k_gemm<2, 128><<<dim3(24, 32), 256, 0, stream>>>(hbuf, 768, W1T + (size_t)l * 3072 * 768, 768,
                                                         b1 + l * 3072, nullptr, mid, nullptr, 3072, 768);
        k_gemm<1, 64><<<dim3(6, 64), 256, 0, stream>>>(mid, 3072, W2T + (size_t)l * 768 * 3072, 3072,
                                                       b2 + l * 768, x, nullptr, x, 768, 3072);
    }

    // ---- final norm + pooling + head ----
    k_ln<u16><<<4096, 256, 0, stream>>>(x, norm_g, norm_b, xn);
    k_gemm<0, 128><<<dim3(12, 32), 256, 0, stream>>>(xn, 768, poolWkvT, 768, pool_bkv, nullptr, poolkv, nullptr, 1536, 768);
    k_qvec<<<768, 64, 0, stream>>>(pool_q, pool_Wq, pool_bq, qvec);
    k_pool_attn<<<BB * MMM * HHH, 256, 0, stream>>>(qvec, poolkv, pad_u8, pr, pooled_pre);
    k_small_mm<<<dim3(12, 32), 256, 0, stream>>>(pooled_pre, pool_Wo, pool_bo, pooled2, 768, 768);
    k_ln<float><<<32, 256, 0, stream>>>(pooled2, mln_g, mln_b, mlnout);
    k_small_mm<<<dim3(9, 32), 256, 0, stream>>>(mlnout, head_W, head_b, outp, 527, 768);
}

// Round 11
// 2061.671 us; speedup vs baseline: 1.0005x; 1.0005x over previous
//
#include <hip/hip_runtime.h>
#include <hip/hip_bf16.h>
#include <math.h>

// Problem constants
#define BB   4
#define NN   1024
#define DD   768
#define HHH  12
#define LLL  12
#define FFD  3072
#define MMM  8
#define CCC  527
#define PDIM 256

typedef unsigned short u16;
typedef __attribute__((ext_vector_type(8))) short bf16x8;
typedef __attribute__((ext_vector_type(4))) float f32x4;

__device__ inline float b2f(u16 x) {
    union { float f; unsigned u; } c; c.u = ((unsigned)x) << 16; return c.f;
}
__device__ inline u16 f2b(float f) {
    __hip_bfloat16 h = __float2bfloat16(f);
    return *reinterpret_cast<u16*>(&h);
}

// exact-GELU via Abramowitz-Stegun 7.1.26 erf (max abs err 1.5e-7) — ~14 VALU ops
__device__ __forceinline__ float gelu_fast(float v) {
    const float x = v * 0.70710678118f;
    const float xa = fabsf(x);
    const float tt = 1.f / (1.f + 0.3275911f * xa);
    const float poly = tt * (0.254829592f + tt * (-0.284496736f + tt * (1.421413741f +
                       tt * (-1.453152027f + tt * 1.061405429f))));
    float er = 1.f - poly * __expf(-xa * xa);
    er = (x < 0.f) ? -er : er;
    return 0.5f * v * (1.f + er);
}

// async global->LDS 16B copy (LDS dest is wave-uniform base + lane*16)
__device__ __forceinline__ void gl_lds16(const u16* g, const u16* l) {
    __builtin_amdgcn_global_load_lds(
        (const __attribute__((address_space(1))) unsigned int*)(unsigned long long)g,
        (__attribute__((address_space(3))) unsigned int*)(unsigned)(unsigned long long)l,
        16, 0, 0);
}

// ---------------- key_pad normalizer: handles bool-as-bytes OR bool-as-int32 ----------------
__global__ void k_pad_norm(const void* __restrict__ p, unsigned char* __restrict__ out, int n) {
    __shared__ int isInt;
    const int t = threadIdx.x;  // single block, 1024 threads
    if (t == 0) isInt = 1;
    __syncthreads();
    const unsigned* up = (const unsigned*)p;
    for (int i = t; i < n / 4; i += 1024) {
        unsigned v = up[i];
        if (v > 1u) isInt = 0;  // benign race
    }
    __syncthreads();
    const int* ip = (const int*)p;
    const unsigned char* cp = (const unsigned char*)p;
    const int mode = isInt;
    for (int i = t; i < n; i += 1024)
        out[i] = mode ? (unsigned char)(ip[i] != 0) : (unsigned char)(cp[i] != 0);
}

// ---------------- weight transpose + f32->bf16 convert (coalesced stores) ----------------
__global__ __launch_bounds__(256) void k_transpose_cvt(
    const float* __restrict__ src, u16* __restrict__ dst,
    int K, int N, long srcLS, long dstLS)
{
    __shared__ float t[64][33];
    const float* s = src + (size_t)blockIdx.z * srcLS;
    u16* d = dst + (size_t)blockIdx.z * dstLS;
    const int n0 = blockIdx.x * 32, k0 = blockIdx.y * 64;
    const int tx = threadIdx.x & 31, ty = threadIdx.x >> 5;  // ty 0..7
    #pragma unroll
    for (int i = 0; i < 8; i++)
        t[ty * 8 + i][tx] = s[(size_t)(k0 + ty * 8 + i) * N + n0 + tx];
    __syncthreads();
    #pragma unroll
    for (int p = 0; p < 4; p++) {
        const int ny = p * 8 + ty;
        union { u16 h[2]; unsigned u; } o;
        o.h[0] = f2b(t[2 * tx][ny]);
        o.h[1] = f2b(t[2 * tx + 1][ny]);
        *(unsigned*)&d[(size_t)(n0 + ny) * K + k0 + 2 * tx] = o.u;
    }
}

// ---------------- plain f32 -> bf16 convert (vectorized) ----------------
__global__ __launch_bounds__(256) void k_cvt(const float* __restrict__ s, u16* __restrict__ d, int n4) {
    int i = blockIdx.x * 256 + threadIdx.x;
    if (i >= n4) return;
    float4 v = ((const float4*)s)[i];
    union { u16 h[4]; uint2 u; } o;
    o.h[0] = f2b(v.x); o.h[1] = f2b(v.y); o.h[2] = f2b(v.z); o.h[3] = f2b(v.w);
    ((uint2*)d)[i] = o.u;
}

// ---------------- pack qkv bias: [L][2304] = concat(bq, bkv) ----------------
__global__ __launch_bounds__(256) void k_bias_pack(const float* __restrict__ bq,
                                                   const float* __restrict__ bkv,
                                                   float* __restrict__ bqkv) {
    int i = blockIdx.x * 256 + threadIdx.x;
    if (i >= LLL * 2304) return;
    int l = i / 2304, c = i % 2304;
    bqkv[i] = (c < 768) ? bq[l * 768 + c] : bkv[l * 1536 + (c - 768)];
}

// ---------------- per-(b,qtile) and per-(b,m) contiguous j ranges ----------------
__global__ void k_ranges(const int* __restrict__ sid, int2* __restrict__ qr, int2* __restrict__ pr) {
    int b = blockIdx.x, t = threadIdx.x;
    const int* s = sid + b * NN;
    if (t < 16) {
        int lo_id = s[t * 64], hi_id = s[t * 64 + 63];
        int lo = 0, hi = NN;
        while (lo < hi) { int mid = (lo + hi) >> 1; if (s[mid] < lo_id) lo = mid + 1; else hi = mid; }
        int l2 = 0, h2 = NN;
        while (l2 < h2) { int mid = (l2 + h2) >> 1; if (s[mid] <= hi_id) l2 = mid + 1; else h2 = mid; }
        qr[b * 16 + t] = make_int2(lo, l2);
    }
    if (t < MMM) {
        int l2 = 0, h2 = NN;
        while (l2 < h2) { int mid = (l2 + h2) >> 1; if (s[mid] < t) l2 = mid + 1; else h2 = mid; }
        int l3 = 0, h3 = NN;
        while (l3 < h3) { int mid = (l3 + h3) >> 1; if (s[mid] <= t) l3 = mid + 1; else h3 = mid; }
        pr[b * MMM + t] = make_int2(l2, l3);
    }
}

// ---------------- LayerNorm: wave-per-row, no LDS/barriers ----------------
// grid = rows/4 blocks x 256 threads (4 waves); lane holds 12 elems (3x float4)
template <typename OT>
__global__ __launch_bounds__(256) void k_ln(const float* __restrict__ x,
                                            const float* __restrict__ g,
                                            const float* __restrict__ b,
                                            OT* __restrict__ out) {
    const int row = blockIdx.x * 4 + (threadIdx.x >> 6);
    const int l = threadIdx.x & 63;
    const float* xr = x + (size_t)row * DD;
    float4 v[3];
    float s1 = 0.f, s2 = 0.f;
    #pragma unroll
    for (int k = 0; k < 3; k++) {
        v[k] = *(const float4*)(xr + k * 256 + l * 4);
        s1 += v[k].x + v[k].y + v[k].z + v[k].w;
        s2 += v[k].x * v[k].x + v[k].y * v[k].y + v[k].z * v[k].z + v[k].w * v[k].w;
    }
    #pragma unroll
    for (int o = 32; o; o >>= 1) { s1 += __shfl_xor(s1, o); s2 += __shfl_xor(s2, o); }
    const float mean = s1 * (1.f / DD);
    const float var = s2 * (1.f / DD) - mean * mean;
    const float rstd = rsqrtf(fmaxf(var, 0.f) + 1e-6f);
    #pragma unroll
    for (int k = 0; k < 3; k++) {
        const int c = k * 256 + l * 4;
        const float4 gg = *(const float4*)(g + c);
        const float4 bb = *(const float4*)(b + c);
        const float r0 = (v[k].x - mean) * rstd * gg.x + bb.x;
        const float r1 = (v[k].y - mean) * rstd * gg.y + bb.y;
        const float r2 = (v[k].z - mean) * rstd * gg.z + bb.z;
        const float r3 = (v[k].w - mean) * rstd * gg.w + bb.w;
        if constexpr (sizeof(OT) == 2) {
            union { u16 h[4]; uint2 u; } o;
            o.h[0] = f2b(r0); o.h[1] = f2b(r1); o.h[2] = f2b(r2); o.h[3] = f2b(r3);
            *(uint2*)&out[(size_t)row * DD + c] = o.u;
        } else {
            float4 o = make_float4(r0, r1, r2, r3);
            *(float4*)&out[(size_t)row * DD + c] = o;
        }
    }
}

// ---------------- bf16 MFMA GEMM, BMx128 tile, 2-deep counted-vmcnt pipeline ----------------
// EPI: 0 = bf16 out, 1 = f32 out + residual (in place), 2 = GELU bf16 out,
//      3 = f32 out, 5 = f32 out + positional embeds (fused embed+posadd)
template <int EPI, int BM>
__global__ __launch_bounds__(256) void k_gemm(
    const u16* __restrict__ A, int lda,
    const u16* __restrict__ Bt, int ldb,
    const float* __restrict__ bias,
    float* __restrict__ Cf, u16* __restrict__ Cb,
    const float* __restrict__ resid,
    int ldc, int K,
    const int* __restrict__ fidx = nullptr, const int* __restrict__ tidx = nullptr,
    const float* __restrict__ pf = nullptr, const float* __restrict__ pt = nullptr)
{
    constexpr int NR  = (BM == 128) ? 4 : 2;     // B-frags per wave
    constexpr int ASZ = BM * 32;                 // u16 per A buffer
    constexpr int BSZ = 128 * 32;
    __shared__ __align__(16) u16 As[3][ASZ];
    __shared__ __align__(16) u16 Bs[3][BSZ];
    const int gx = gridDim.x;
    const int nwg = gx * gridDim.y;
    int bid = blockIdx.y * gx + blockIdx.x;
    if ((nwg & 7) == 0) bid = (bid & 7) * (nwg >> 3) + (bid >> 3);
    const int row0 = (bid / gx) * BM, col0 = (bid % gx) * 128;
    const int t = threadIdx.x;
    const int w = t >> 6, lane = t & 63;
    const int wr = (BM == 128) ? (w >> 1) * 64 : 0;
    const int wc = (BM == 128) ? (w & 1) * 64 : w * 32;
    const int fr = lane & 15, fg = lane >> 4;
    const int srow = t >> 2, sseg = (t & 3) * 8;     // sseg in u16 elems
    const u16* Ap = A + (size_t)(row0 + srow) * lda + sseg;
    const u16* Bp = Bt + (size_t)(col0 + srow) * ldb + sseg;
    const size_t lstep = (size_t)64 * lda, bstep = (size_t)64 * ldb;

    auto stage = [&](int buf, int k0) {
        #pragma unroll
        for (int i = 0; i < BM / 64; i++)
            gl_lds16(Ap + i * lstep + k0, &As[buf][i * 2048 + t * 8]);
        #pragma unroll
        for (int i = 0; i < 2; i++)
            gl_lds16(Bp + i * bstep + k0, &Bs[buf][i * 2048 + t * 8]);
    };

    f32x4 acc[4][NR];
    #pragma unroll
    for (int m = 0; m < 4; m++)
        #pragma unroll
        for (int n = 0; n < NR; n++) acc[m][n] = (f32x4){0.f, 0.f, 0.f, 0.f};

    const int nt = K >> 5;
    stage(0, 0);
    stage(1, 32);

    for (int kt = 0; kt < nt; ++kt) {
        if (kt + 1 < nt) {
            if constexpr (BM == 128) asm volatile("s_waitcnt vmcnt(4)" ::: "memory");
            else                     asm volatile("s_waitcnt vmcnt(3)" ::: "memory");
        } else {
            asm volatile("s_waitcnt vmcnt(0)" ::: "memory");
        }
        __builtin_amdgcn_s_barrier();
        __builtin_amdgcn_sched_barrier(0);
        if (kt + 2 < nt) stage((kt + 2) % 3, (kt + 2) * 32);
        const int cur = kt % 3;
        bf16x8 af[4], bfr[NR];
        #pragma unroll
        for (int m = 0; m < 4; m++) af[m] = *(const bf16x8*)&As[cur][(wr + m * 16 + fr) * 32 + fg * 8];
        #pragma unroll
        for (int n = 0; n < NR; n++) bfr[n] = *(const bf16x8*)&Bs[cur][(wc + n * 16 + fr) * 32 + fg * 8];
        __builtin_amdgcn_s_setprio(1);
        #pragma unroll
        for (int m = 0; m < 4; m++)
            #pragma unroll
            for (int n = 0; n < NR; n++)
                acc[m][n] = __builtin_amdgcn_mfma_f32_16x16x32_bf16(af[m], bfr[n], acc[m][n], 0, 0, 0);
        __builtin_amdgcn_s_setprio(0);
    }
    #pragma unroll
    for (int m = 0; m < 4; m++) {
        #pragma unroll
        for (int n = 0; n < NR; n++) {
            const int col = col0 + wc + n * 16 + fr;
            const float bb = bias[col];
            #pragma unroll
            for (int r = 0; r < 4; r++) {
                const size_t row = row0 + wr + m * 16 + fg * 4 + r;
                float v = acc[m][n][r] + bb;
                if (EPI == 0) {
                    Cb[row * ldc + col] = f2b(v);
                } else if (EPI == 1) {
                    Cf[row * ldc + col] = v + resid[row * ldc + col];
                } else if (EPI == 2) {
                    Cb[row * ldc + col] = f2b(gelu_fast(v));
                } else if (EPI == 3) {
                    Cf[row * ldc + col] = v;
                } else if (EPI == 5) {
                    const int fi = fidx[row], ti = tidx[row];
                    Cf[row * ldc + col] = v + pf[(size_t)fi * DD + col] + pt[(size_t)ti * DD + col];
                }
            }
        }
    }
}

// ---------------- block-diagonal flash attention (no 1/sqrt(d) scaling) ----------------
// Double-buffered K/V LDS, single barrier per j-tile; Q staged through K-buf1
// (consumed into regs before K1's first write, protected by prologue barriers).
__global__ __launch_bounds__(256) void k_attn(
    const u16* __restrict__ qkv,
    const int* __restrict__ sid, const unsigned char* __restrict__ pad,
    const int2* __restrict__ qr,
    u16* __restrict__ outb)
{
    // LDS pool (u16 units): K0[4608] K1[4608] V0[4640] V1[4640] Ps[4608]  (~46.2 KB)
    __shared__ __align__(16) u16 pool[2 * 4608 + 2 * 4640 + 4608];
    u16* const K0  = pool;
    u16* const K1  = pool + 4608;
    u16* const V0  = pool + 9216;
    u16* const V1  = pool + 9216 + 4640;
    u16* const PsB = pool + 9216 + 9280;
    __shared__ int sidq[64];
    __shared__ int sidj[2][64];
    __shared__ int padj[2][64];
    const int b = blockIdx.z, h = blockIdx.y, qt = blockIdx.x;
    const int i0 = qt * 64;
    const int t = threadIdx.x, w = t >> 6, lane = t & 63;
    const int fr = lane & 15, fg = lane >> 4;
    const int srow = t >> 2, sseg = (t & 3) * 16;
    const int goff = (sseg >> 4) << 3;           // V swizzle offset, constant per thread
    const size_t tokbase = (size_t)b * NN;
    const u16* qbase = qkv + (tokbase + i0) * 2304 + h * 64;
    // stage Q via K1 region
    *(uint4*)&K1[srow * 72 + sseg]     = *(const uint4*)(qbase + (size_t)srow * 2304 + sseg);
    *(uint4*)&K1[srow * 72 + sseg + 8] = *(const uint4*)(qbase + (size_t)srow * 2304 + sseg + 8);
    if (t < 64) sidq[t] = sid[tokbase + i0 + t];
    __syncthreads();
    const bf16x8 qf0 = *(const bf16x8*)&K1[(w * 16 + fr) * 72 + fg * 8];
    const bf16x8 qf1 = *(const bf16x8*)&K1[(w * 16 + fr) * 72 + 32 + fg * 8];
    const int myrow = w * 16 + fg * 4;
    float m_run[4], l_run[4];
    f32x4 oacc[4];
    #pragma unroll
    for (int r = 0; r < 4; r++) { m_run[r] = -1e30f; l_run[r] = 0.f; }
    #pragma unroll
    for (int n = 0; n < 4; n++) oacc[n] = (f32x4){0.f, 0.f, 0.f, 0.f};
    const int2 rg = qr[b * 16 + qt];
    const u16* kbase = qkv + tokbase * 2304 + 768 + h * 64;
    const u16* vbase = qkv + tokbase * 2304 + 1536 + h * 64;
    const int jstart = rg.x & ~63;
    const int ntiles = (rg.y - jstart + 63) >> 6;

    // reg prefetch state
    uint4 rk0, rk1, rv0, rv1;
    int rsid = 0, rpad = 0;
    auto load_tile = [&](int tile) {
        const size_t ro = (size_t)(jstart + tile * 64 + srow) * 2304;
        rk0 = *(const uint4*)(kbase + ro + sseg);
        rk1 = *(const uint4*)(kbase + ro + sseg + 8);
        rv0 = *(const uint4*)(vbase + ro + sseg);
        rv1 = *(const uint4*)(vbase + ro + sseg + 8);
        if (t < 64) { rsid = sid[tokbase + jstart + tile * 64 + t]; rpad = pad[tokbase + jstart + tile * 64 + t]; }
    };
    auto write_tile = [&](u16* kb, u16* vb, int slot) {
        *(uint4*)&kb[srow * 72 + sseg]     = rk0;
        *(uint4*)&kb[srow * 72 + sseg + 8] = rk1;
        u16 tmp[16];
        *(uint4*)&tmp[0] = rv0;
        *(uint4*)&tmp[8] = rv1;
        #pragma unroll
        for (int e = 0; e < 16; e++)
            vb[(sseg + e) * 72 + goff + srow] = tmp[e];
        if (t < 64) { sidj[slot][t] = rsid; padj[slot][t] = rpad; }
    };

    // prologue: tile0 -> buf0 (K0/V0: no overlap with Q in K1); tile1 -> regs
    load_tile(0);
    write_tile(K0, V0, 0);
    if (ntiles > 1) load_tile(1);
    __syncthreads();   // Q-frag reads done + tile0 visible

    for (int tt = 0; tt < ntiles; ++tt) {
        const int cb = tt & 1;
        u16* const kb = cb ? K1 : K0;
        u16* const vb = cb ? V1 : V0;
        if (tt + 1 < ntiles) {
            // write tile tt+1 into the other buffer (its last readers finished at iter tt-1's barrier)
            write_tile(cb ? K0 : K1, cb ? V0 : V1, cb ^ 1);
            if (tt + 2 < ntiles) load_tile(tt + 2);
        }
        // S = Q K^T  (16 q-rows per wave x 64 j)
        f32x4 s[4];
        __builtin_amdgcn_s_setprio(1);
        #pragma unroll
        for (int nj = 0; nj < 4; nj++) {
            bf16x8 kf0 = *(const bf16x8*)&kb[(nj * 16 + fr) * 72 + fg * 8];
            bf16x8 kf1 = *(const bf16x8*)&kb[(nj * 16 + fr) * 72 + 32 + fg * 8];
            f32x4 a = (f32x4){0.f, 0.f, 0.f, 0.f};
            a = __builtin_amdgcn_mfma_f32_16x16x32_bf16(qf0, kf0, a, 0, 0, 0);
            a = __builtin_amdgcn_mfma_f32_16x16x32_bf16(qf1, kf1, a, 0, 0, 0);
            s[nj] = a;
        }
        __builtin_amdgcn_s_setprio(0);
        // mask
        #pragma unroll
        for (int nj = 0; nj < 4; nj++) {
            const int jj = nj * 16 + fr;
            const int sj = sidj[cb][jj];
            const int pd = padj[cb][jj];
            #pragma unroll
            for (int r = 0; r < 4; r++) {
                const bool ok = pd && (sj == sidq[myrow + r]);
                s[nj][r] = ok ? s[nj][r] : -3e38f;
            }
        }
        // online softmax (rows live on 16-lane groups)
        float mnew[4], scale[4];
        #pragma unroll
        for (int r = 0; r < 4; r++) {
            float mx = fmaxf(fmaxf(s[0][r], s[1][r]), fmaxf(s[2][r], s[3][r]));
            #pragma unroll
            for (int o = 1; o < 16; o <<= 1) mx = fmaxf(mx, __shfl_xor(mx, o));
            mnew[r] = fmaxf(m_run[r], mx);
            scale[r] = __expf(m_run[r] - mnew[r]);
            m_run[r] = mnew[r];
        }
        #pragma unroll
        for (int r = 0; r < 4; r++) {
            float rs = 0.f;
            #pragma unroll
            for (int nj = 0; nj < 4; nj++) {
                float pv = __expf(s[nj][r] - mnew[r]);
                rs += pv;
                PsB[(w * 16 + fg * 4 + r) * 72 + nj * 16 + fr] = f2b(pv);
            }
            #pragma unroll
            for (int o = 1; o < 16; o <<= 1) rs += __shfl_xor(rs, o);
            l_run[r] = l_run[r] * scale[r] + rs;
        }
        #pragma unroll
        for (int n = 0; n < 4; n++)
            #pragma unroll
            for (int r = 0; r < 4; r++) oacc[n][r] *= scale[r];
        // O += P V   (P via per-wave LDS relayout; same-wave DS ordering is program order)
        bf16x8 pa0 = *(const bf16x8*)&PsB[(w * 16 + fr) * 72 + fg * 8];
        bf16x8 pa1 = *(const bf16x8*)&PsB[(w * 16 + fr) * 72 + 32 + fg * 8];
        __builtin_amdgcn_s_setprio(1);
        #pragma unroll
        for (int nd = 0; nd < 4; nd++) {
            bf16x8 vf0 = *(const bf16x8*)&vb[(nd * 16 + fr) * 72 + nd * 8 + fg * 8];
            bf16x8 vf1 = *(const bf16x8*)&vb[(nd * 16 + fr) * 72 + nd * 8 + 32 + fg * 8];
            oacc[nd] = __builtin_amdgcn_mfma_f32_16x16x32_bf16(pa0, vf0, oacc[nd], 0, 0, 0);
            oacc[nd] = __builtin_amdgcn_mfma_f32_16x16x32_bf16(pa1, vf1, oacc[nd], 0, 0, 0);
        }
        __builtin_amdgcn_s_setprio(0);
        __syncthreads();   // readers of buf[tt] done; writes of buf[tt+1] visible
    }
    float inv[4];
    #pragma unroll
    for (int r = 0; r < 4; r++) inv[r] = 1.f / l_run[r];
    #pragma unroll
    for (int nd = 0; nd < 4; nd++)
        #pragma unroll
        for (int r = 0; r < 4; r++)
            outb[(tokbase + i0 + myrow + r) * DD + h * 64 + nd * 16 + fr] = f2b(oacc[nd][r] * inv[r]);
}

// ---------------- pool query vector: qv[c] = pool_q . pool_Wq[:,c] + pool_bq[c] ----------------
__global__ __launch_bounds__(64) void k_qvec(const float* __restrict__ pq, const float* __restrict__ Wq,
                                             const float* __restrict__ bq, float* __restrict__ qv) {
    int c = blockIdx.x;
    int l = threadIdx.x;
    float s = 0.f;
    #pragma unroll
    for (int d = l; d < DD; d += 64) s += pq[d] * Wq[(size_t)d * DD + c];
    #pragma unroll
    for (int o = 32; o; o >>= 1) s += __shfl_xor(s, o);
    if (l == 0) qv[c] = s + bq[c];
}

// ---------------- attention pooling: one block per (b, m, h) ----------------
__global__ __launch_bounds__(256) void k_pool_attn(
    const float* __restrict__ qv, const u16* __restrict__ kv,
    const unsigned char* __restrict__ pad, const int2* __restrict__ pr,
    float* __restrict__ outp)
{
    const int idx = blockIdx.x;                 // ((b*8+m)*12+h)
    const int h = idx % HHH, bm = idx / HHH;
    const int b = bm >> 3, m = bm & 7;
    const int2 rg = pr[b * MMM + m];
    const int lo = rg.x, cnt = rg.y - rg.x;
    __shared__ float sc[NN];
    __shared__ float qsh[64];
    __shared__ float rbuf[4];
    __shared__ float vacc[4][64];
    if (threadIdx.x < 64) qsh[threadIdx.x] = qv[h * 64 + threadIdx.x];
    __syncthreads();
    // scores (vectorized 16B K loads)
    for (int j = threadIdx.x; j < cnt; j += 256) {
        const u16* krow = kv + (size_t)(b * NN + lo + j) * 1536 + h * 64;
        float s = 0.f;
        #pragma unroll
        for (int dv = 0; dv < 8; dv++) {
            bf16x8 k8 = *(const bf16x8*)(krow + dv * 8);
            #pragma unroll
            for (int e = 0; e < 8; e++) s += qsh[dv * 8 + e] * b2f((u16)k8[e]);
        }
        sc[j] = pad[b * NN + lo + j] ? s : -3e38f;
    }
    __syncthreads();
    float mx = -3e38f;
    for (int j = threadIdx.x; j < cnt; j += 256) mx = fmaxf(mx, sc[j]);
    #pragma unroll
    for (int o = 32; o; o >>= 1) mx = fmaxf(mx, __shfl_xor(mx, o));
    if ((threadIdx.x & 63) == 0) rbuf[threadIdx.x >> 6] = mx;
    __syncthreads();
    mx = fmaxf(fmaxf(rbuf[0], rbuf[1]), fmaxf(rbuf[2], rbuf[3]));
    __syncthreads();
    float sm = 0.f;
    for (int j = threadIdx.x; j < cnt; j += 256) { float p = __expf(sc[j] - mx); sc[j] = p; sm += p; }
    #pragma unroll
    for (int o = 32; o; o >>= 1) sm += __shfl_xor(sm, o);
    if ((threadIdx.x & 63) == 0) rbuf[threadIdx.x >> 6] = sm;
    __syncthreads();
    sm = rbuf[0] + rbuf[1] + rbuf[2] + rbuf[3];
    const float inv = 1.f / sm;
    {
        const int d = threadIdx.x & 63, g = threadIdx.x >> 6;
        float acc = 0.f;
        for (int j = g; j < cnt; j += 4)
            acc += sc[j] * b2f(kv[(size_t)(b * NN + lo + j) * 1536 + 768 + h * 64 + d]);
        vacc[g][d] = acc;
        __syncthreads();
        if (g == 0)
            outp[(size_t)(b * MMM + m) * DD + h * 64 + d] =
                (vacc[0][d] + vacc[1][d] + vacc[2][d] + vacc[3][d]) * inv;
    }
}

// ---------------- small f32 GEMM: out[32][N] = A[32][768] @ W[768][N] + bias ----------------
__global__ __launch_bounds__(256) void k_small_mm(const float* __restrict__ A, const float* __restrict__ W,
                                                  const float* __restrict__ bias, float* __restrict__ out,
                                                  int N, int Kd) {
    const int row = blockIdx.y;
    const int cl = threadIdx.x & 63, kg = threadIdx.x >> 6;
    const int c = blockIdx.x * 64 + cl;
    const int cload = (c < N) ? c : (N - 1);
    __shared__ float As[DD];
    __shared__ float red[4][64];
    for (int d = threadIdx.x; d < Kd; d += 256) As[d] = A[(size_t)row * Kd + d];
    __syncthreads();
    const int kper = Kd >> 2;
    const int kbase = kg * kper;
    float s = 0.f;
    const float* w = W + (size_t)kbase * N + cload;
    #pragma unroll 4
    for (int i = 0; i < kper; i++) s += As[kbase + i] * w[(size_t)i * N];
    red[kg][cl] = s;
    __syncthreads();
    if (kg == 0 && c < N)
        out[(size_t)row * N + c] = red[0][cl] + red[1][cl] + red[2][cl] + red[3][cl] + bias[c];
}

// =======================================================================
extern "C" void kernel_launch(void* const* d_in, const int* in_sizes, int n_in,
                              void* d_out, int out_size, void* d_ws, size_t ws_size,
                              hipStream_t stream) {
    const float* patches   = (const float*)d_in[0];
    const int*   sample_ids= (const int*)d_in[1];
    const void*  key_pad_raw = (const void*)d_in[2];   // bool: byte OR int32 — normalized below
    const int*   freq_idx  = (const int*)d_in[3];
    const int*   time_idx  = (const int*)d_in[4];
    const float* patch_W   = (const float*)d_in[5];
    const float* patch_b   = (const float*)d_in[6];
    const float* pos_f     = (const float*)d_in[7];
    const float* pos_t     = (const float*)d_in[8];
    const float* ln1_g     = (const float*)d_in[9];
    const float* ln1_b     = (const float*)d_in[10];
    const float* Wq        = (const float*)d_in[11];
    const float* bq        = (const float*)d_in[12];
    const float* Wkv       = (const float*)d_in[13];
    const float* bkv       = (const float*)d_in[14];
    const float* Wo        = (const float*)d_in[15];
    const float* bo        = (const float*)d_in[16];
    const float* ln2_g     = (const float*)d_in[17];
    const float* ln2_b     = (const float*)d_in[18];
    const float* W1        = (const float*)d_in[19];
    const float* b1        = (const float*)d_in[20];
    const float* W2        = (const float*)d_in[21];
    const float* b2        = (const float*)d_in[22];
    const float* norm_g    = (const float*)d_in[23];
    const float* norm_b    = (const float*)d_in[24];
    const float* pool_q    = (const float*)d_in[25];
    const float* pool_Wq   = (const float*)d_in[26];
    const float* pool_bq   = (const float*)d_in[27];
    const float* pool_Wkv  = (const float*)d_in[28];
    const float* pool_bkv  = (const float*)d_in[29];
    const float* pool_Wo   = (const float*)d_in[30];
    const float* pool_bo   = (const float*)d_in[31];
    const float* mln_g     = (const float*)d_in[32];
    const float* mln_b     = (const float*)d_in[33];
    const float* head_W    = (const float*)d_in[34];
    const float* head_b    = (const float*)d_in[35];
    float* outp = (float*)d_out;
    (void)in_sizes; (void)n_in; (void)out_size; (void)ws_size;

    char* ws = (char*)d_ws;
    size_t off = 0;
    auto alloc = [&](size_t bytes) -> void* {
        void* p = (void*)(ws + off);
        off += (bytes + 255) & ~(size_t)255;
        return p;
    };
    // persistent: bf16 transposed weights (~165 MB)
    u16* WqkvT    = (u16*)alloc((size_t)LLL * 2304 * 768 * 2);
    u16* WoT      = (u16*)alloc((size_t)LLL * 768 * 768 * 2);
    u16* W1T      = (u16*)alloc((size_t)LLL * 3072 * 768 * 2);
    u16* W2T      = (u16*)alloc((size_t)LLL * 768 * 3072 * 2);
    u16* patchWT  = (u16*)alloc((size_t)768 * 256 * 2);
    u16* poolWkvT = (u16*)alloc((size_t)1536 * 768 * 2);
    float* bqkv   = (float*)alloc((size_t)LLL * 2304 * 4);
    unsigned char* pad_u8 = (unsigned char*)alloc(BB * NN);
    // activations (~66 MB, with aliasing)
    float* x      = (float*)alloc((size_t)4096 * 768 * 4);
    u16* hbuf     = (u16*)alloc((size_t)4096 * 768 * 2);
    u16* qkvb     = (u16*)alloc((size_t)4096 * 2304 * 2);
    u16* attno    = (u16*)alloc((size_t)4096 * 768 * 2);
    u16* mid      = (u16*)alloc((size_t)4096 * 3072 * 2);
    u16* patch_bf = mid;     // alias: patch_bf (4096x256) dead before first W1 GEMM
    u16* xn       = attno;   // alias: xn written after last attno read
    u16* poolkv   = qkvb;    // alias: poolkv written after last qkvb read
    float* qvec   = (float*)alloc(768 * 4);
    float* pooled_pre = (float*)alloc(32 * 768 * 4);
    float* pooled2    = (float*)alloc(32 * 768 * 4);
    float* mlnout     = (float*)alloc(32 * 768 * 4);
    int2* qr = (int2*)alloc(4 * 16 * sizeof(int2));
    int2* pr = (int2*)alloc(4 * 8 * sizeof(int2));

    // ---- input prep ----
    k_pad_norm<<<1, 1024, 0, stream>>>(key_pad_raw, pad_u8, BB * NN);
    k_transpose_cvt<<<dim3(24, 12, LLL), 256, 0, stream>>>(Wq, WqkvT, 768, 768, (long)768 * 768, (long)2304 * 768);
    k_transpose_cvt<<<dim3(48, 12, LLL), 256, 0, stream>>>(Wkv, WqkvT + (size_t)768 * 768, 768, 1536, (long)768 * 1536, (long)2304 * 768);
    k_transpose_cvt<<<dim3(24, 12, LLL), 256, 0, stream>>>(Wo, WoT, 768, 768, (long)768 * 768, (long)768 * 768);
    k_transpose_cvt<<<dim3(96, 12, LLL), 256, 0, stream>>>(W1, W1T, 768, 3072, (long)768 * 3072, (long)3072 * 768);
    k_transpose_cvt<<<dim3(24, 48, LLL), 256, 0, stream>>>(W2, W2T, 3072, 768, (long)3072 * 768, (long)768 * 3072);
    k_transpose_cvt<<<dim3(24, 4, 1), 256, 0, stream>>>(patch_W, patchWT, 256, 768, 0, 0);
    k_transpose_cvt<<<dim3(48, 12, 1), 256, 0, stream>>>(pool_Wkv, poolWkvT, 768, 1536, 0, 0);
    k_cvt<<<1024, 256, 0, stream>>>(patches, patch_bf, 4096 * 256 / 4);
    k_bias_pack<<<(LLL * 2304 + 255) / 256, 256, 0, stream>>>(bq, bkv, bqkv);
    k_ranges<<<4, 64, 0, stream>>>(sample_ids, qr, pr);

    // ---- embed + positional (fused epilogue) ----
    k_gemm<5, 64><<<dim3(6, 64), 256, 0, stream>>>(patch_bf, 256, patchWT, 256, patch_b, x, nullptr, nullptr,
                                                   768, 256, freq_idx, time_idx, pos_f, pos_t);

    // ---- transformer layers ----
    for (int l = 0; l < LLL; l++) {
        k_ln<u16><<<1024, 256, 0, stream>>>(x, ln1_g + l * 768, ln1_b + l * 768, hbuf);
        k_gemm<0, 128><<<dim3(18, 32), 256, 0, stream>>>(hbuf, 768, WqkvT + (size_t)l * 2304 * 768, 768,
                                                         bqkv + l * 2304, nullptr, qkvb, nullptr, 2304, 768);
        k_attn<<<dim3(16, 12, 4), 256, 0, stream>>>(qkvb, sample_ids, pad_u8, qr, attno);
        k_gemm<1, 64><<<dim3(6, 64), 256, 0, stream>>>(attno, 768, WoT + (size_t)l * 768 * 768, 768,
                                                       bo + l * 768, x, nullptr, x, 768, 768);
        k_ln<u16><<<1024, 256, 0, stream>>>(x, ln2_g + l * 768, ln2_b + l * 768, hbuf);
        k_gemm<2, 128><<<dim3(24, 32), 256, 0, stream>>>(hbuf, 768, W1T + (size_t)l * 3072 * 768, 768,
                                                         b1 + l * 3072, nullptr, mid, nullptr, 3072, 768);
        k_gemm<1, 64><<<dim3(6, 64), 256, 0, stream>>>(mid, 3072, W2T + (size_t)l * 768 * 3072, 3072,
                                                       b2 + l * 768, x, nullptr, x, 768, 3072);
    }

    // ---- final norm + pooling + head ----
    k_ln<u16><<<1024, 256, 0, stream>>>(x, norm_g, norm_b, xn);
    k_gemm<0, 128><<<dim3(12, 32), 256, 0, stream>>>(xn, 768, poolWkvT, 768, pool_bkv, nullptr, poolkv, nullptr, 1536, 768);
    k_qvec<<<768, 64, 0, stream>>>(pool_q, pool_Wq, pool_bq, qvec);
    k_pool_attn<<<BB * MMM * HHH, 256, 0, stream>>>(qvec, poolkv, pad_u8, pr, pooled_pre);
    k_small_mm<<<dim3(12, 32), 256, 0, stream>>>(pooled_pre, pool_Wo, pool_bo, pooled2, 768, 768);
    k_ln<float><<<8, 256, 0, stream>>>(pooled2, mln_g, mln_b, mlnout);
    k_small_mm<<<dim3(9, 32), 256, 0, stream>>>(mlnout, head_W, head_b, outp, 527, 768);
}

// Round 13
// 2013.677 us; speedup vs baseline: 1.0244x; 1.0238x over previous
//
#include <hip/hip_runtime.h>
#include <hip/hip_bf16.h>
#include <math.h>

// Problem constants
#define BB   4
#define NN   1024
#define DD   768
#define HHH  12
#define LLL  12
#define FFD  3072
#define MMM  8
#define CCC  527
#define PDIM 256

typedef unsigned short u16;
typedef __attribute__((ext_vector_type(8))) short bf16x8;
typedef __attribute__((ext_vector_type(4))) float f32x4;

__device__ inline float b2f(u16 x) {
    union { float f; unsigned u; } c; c.u = ((unsigned)x) << 16; return c.f;
}
__device__ inline u16 f2b(float f) {
    __hip_bfloat16 h = __float2bfloat16(f);
    return *reinterpret_cast<u16*>(&h);
}

// exact-GELU via Abramowitz-Stegun 7.1.26 erf (max abs err 1.5e-7) — ~14 VALU ops
__device__ __forceinline__ float gelu_fast(float v) {
    const float x = v * 0.70710678118f;
    const float xa = fabsf(x);
    const float tt = 1.f / (1.f + 0.3275911f * xa);
    const float poly = tt * (0.254829592f + tt * (-0.284496736f + tt * (1.421413741f +
                       tt * (-1.453152027f + tt * 1.061405429f))));
    float er = 1.f - poly * __expf(-xa * xa);
    er = (x < 0.f) ? -er : er;
    return 0.5f * v * (1.f + er);
}

// async global->LDS 16B copy (LDS dest is wave-uniform base + lane*16)
__device__ __forceinline__ void gl_lds16(const u16* g, const u16* l) {
    __builtin_amdgcn_global_load_lds(
        (const __attribute__((address_space(1))) unsigned int*)(unsigned long long)g,
        (__attribute__((address_space(3))) unsigned int*)(unsigned)(unsigned long long)l,
        16, 0, 0);
}

// ---------------- key_pad normalizer: handles bool-as-bytes OR bool-as-int32 ----------------
__global__ void k_pad_norm(const void* __restrict__ p, unsigned char* __restrict__ out, int n) {
    __shared__ int isInt;
    const int t = threadIdx.x;  // single block, 1024 threads
    if (t == 0) isInt = 1;
    __syncthreads();
    const unsigned* up = (const unsigned*)p;
    for (int i = t; i < n / 4; i += 1024) {
        unsigned v = up[i];
        if (v > 1u) isInt = 0;  // benign race
    }
    __syncthreads();
    const int* ip = (const int*)p;
    const unsigned char* cp = (const unsigned char*)p;
    const int mode = isInt;
    for (int i = t; i < n; i += 1024)
        out[i] = mode ? (unsigned char)(ip[i] != 0) : (unsigned char)(cp[i] != 0);
}

// ---------------- weight transpose + f32->bf16 convert (coalesced stores) ----------------
__global__ __launch_bounds__(256) void k_transpose_cvt(
    const float* __restrict__ src, u16* __restrict__ dst,
    int K, int N, long srcLS, long dstLS)
{
    __shared__ float t[64][33];
    const float* s = src + (size_t)blockIdx.z * srcLS;
    u16* d = dst + (size_t)blockIdx.z * dstLS;
    const int n0 = blockIdx.x * 32, k0 = blockIdx.y * 64;
    const int tx = threadIdx.x & 31, ty = threadIdx.x >> 5;  // ty 0..7
    #pragma unroll
    for (int i = 0; i < 8; i++)
        t[ty * 8 + i][tx] = s[(size_t)(k0 + ty * 8 + i) * N + n0 + tx];
    __syncthreads();
    #pragma unroll
    for (int p = 0; p < 4; p++) {
        const int ny = p * 8 + ty;
        union { u16 h[2]; unsigned u; } o;
        o.h[0] = f2b(t[2 * tx][ny]);
        o.h[1] = f2b(t[2 * tx + 1][ny]);
        *(unsigned*)&d[(size_t)(n0 + ny) * K + k0 + 2 * tx] = o.u;
    }
}

// ---------------- plain f32 -> bf16 convert (vectorized) ----------------
__global__ __launch_bounds__(256) void k_cvt(const float* __restrict__ s, u16* __restrict__ d, int n4) {
    int i = blockIdx.x * 256 + threadIdx.x;
    if (i >= n4) return;
    float4 v = ((const float4*)s)[i];
    union { u16 h[4]; uint2 u; } o;
    o.h[0] = f2b(v.x); o.h[1] = f2b(v.y); o.h[2] = f2b(v.z); o.h[3] = f2b(v.w);
    ((uint2*)d)[i] = o.u;
}

// ---------------- pack qkv bias: [L][2304] = concat(bq, bkv) ----------------
__global__ __launch_bounds__(256) void k_bias_pack(const float* __restrict__ bq,
                                                   const float* __restrict__ bkv,
                                                   float* __restrict__ bqkv) {
    int i = blockIdx.x * 256 + threadIdx.x;
    if (i >= LLL * 2304) return;
    int l = i / 2304, c = i % 2304;
    bqkv[i] = (c < 768) ? bq[l * 768 + c] : bkv[l * 1536 + (c - 768)];
}

// ---------------- per-(b,qtile) and per-(b,m) contiguous j ranges ----------------
__global__ void k_ranges(const int* __restrict__ sid, int2* __restrict__ qr, int2* __restrict__ pr) {
    int b = blockIdx.x, t = threadIdx.x;
    const int* s = sid + b * NN;
    if (t < 16) {
        int lo_id = s[t * 64], hi_id = s[t * 64 + 63];
        int lo = 0, hi = NN;
        while (lo < hi) { int mid = (lo + hi) >> 1; if (s[mid] < lo_id) lo = mid + 1; else hi = mid; }
        int l2 = 0, h2 = NN;
        while (l2 < h2) { int mid = (l2 + h2) >> 1; if (s[mid] <= hi_id) l2 = mid + 1; else h2 = mid; }
        qr[b * 16 + t] = make_int2(lo, l2);
    }
    if (t < MMM) {
        int l2 = 0, h2 = NN;
        while (l2 < h2) { int mid = (l2 + h2) >> 1; if (s[mid] < t) l2 = mid + 1; else h2 = mid; }
        int l3 = 0, h3 = NN;
        while (l3 < h3) { int mid = (l3 + h3) >> 1; if (s[mid] <= t) l3 = mid + 1; else h3 = mid; }
        pr[b * MMM + t] = make_int2(l2, l3);
    }
}

// ---------------- LayerNorm: wave-per-row, no LDS/barriers ----------------
template <typename OT>
__global__ __launch_bounds__(256) void k_ln(const float* __restrict__ x,
                                            const float* __restrict__ g,
                                            const float* __restrict__ b,
                                            OT* __restrict__ out) {
    const int row = blockIdx.x * 4 + (threadIdx.x >> 6);
    const int l = threadIdx.x & 63;
    const float* xr = x + (size_t)row * DD;
    float4 v[3];
    float s1 = 0.f, s2 = 0.f;
    #pragma unroll
    for (int k = 0; k < 3; k++) {
        v[k] = *(const float4*)(xr + k * 256 + l * 4);
        s1 += v[k].x + v[k].y + v[k].z + v[k].w;
        s2 += v[k].x * v[k].x + v[k].y * v[k].y + v[k].z * v[k].z + v[k].w * v[k].w;
    }
    #pragma unroll
    for (int o = 32; o; o >>= 1) { s1 += __shfl_xor(s1, o); s2 += __shfl_xor(s2, o); }
    const float mean = s1 * (1.f / DD);
    const float var = s2 * (1.f / DD) - mean * mean;
    const float rstd = rsqrtf(fmaxf(var, 0.f) + 1e-6f);
    #pragma unroll
    for (int k = 0; k < 3; k++) {
        const int c = k * 256 + l * 4;
        const float4 gg = *(const float4*)(g + c);
        const float4 bb = *(const float4*)(b + c);
        const float r0 = (v[k].x - mean) * rstd * gg.x + bb.x;
        const float r1 = (v[k].y - mean) * rstd * gg.y + bb.y;
        const float r2 = (v[k].z - mean) * rstd * gg.z + bb.z;
        const float r3 = (v[k].w - mean) * rstd * gg.w + bb.w;
        if constexpr (sizeof(OT) == 2) {
            union { u16 h[4]; uint2 u; } o;
            o.h[0] = f2b(r0); o.h[1] = f2b(r1); o.h[2] = f2b(r2); o.h[3] = f2b(r3);
            *(uint2*)&out[(size_t)row * DD + c] = o.u;
        } else {
            float4 o = make_float4(r0, r1, r2, r3);
            *(float4*)&out[(size_t)row * DD + c] = o;
        }
    }
}

// ---------------- bf16 MFMA GEMM, BMx128 tile, 2-deep counted-vmcnt pipeline ----------------
// T2 segment swizzle (rule #21 compliant): LDS dest LINEAR (gl_lds16), global source
// k-segment pre-swizzled by seg^((row>>1)&3); frag read uses slot fg^((R>>1)&3).
// 16-lane fr-groups then cover all 8 bank-quad combos 2x each -> conflict-free b128 reads.
// EPI: 0 = bf16 out, 1 = f32 out + residual (in place), 2 = GELU bf16 out,
//      3 = f32 out, 5 = f32 out + positional embeds (fused embed+posadd)
template <int EPI, int BM>
__global__ __launch_bounds__(256) void k_gemm(
    const u16* __restrict__ A, int lda,
    const u16* __restrict__ Bt, int ldb,
    const float* __restrict__ bias,
    float* __restrict__ Cf, u16* __restrict__ Cb,
    const float* __restrict__ resid,
    int ldc, int K,
    const int* __restrict__ fidx = nullptr, const int* __restrict__ tidx = nullptr,
    const float* __restrict__ pf = nullptr, const float* __restrict__ pt = nullptr)
{
    constexpr int NR  = (BM == 128) ? 4 : 2;     // B-frags per wave
    constexpr int ASZ = BM * 32;                 // u16 per A buffer
    constexpr int BSZ = 128 * 32;
    __shared__ __align__(16) u16 As[3][ASZ];
    __shared__ __align__(16) u16 Bs[3][BSZ];
    const int gx = gridDim.x;
    const int nwg = gx * gridDim.y;
    int bid = blockIdx.y * gx + blockIdx.x;
    if ((nwg & 7) == 0) bid = (bid & 7) * (nwg >> 3) + (bid >> 3);
    const int row0 = (bid / gx) * BM, col0 = (bid % gx) * 128;
    const int t = threadIdx.x;
    const int w = t >> 6, lane = t & 63;
    const int wr = (BM == 128) ? (w >> 1) * 64 : 0;
    const int wc = (BM == 128) ? (w & 1) * 64 : w * 32;
    const int fr = lane & 15, fg = lane >> 4;
    const int srow = t >> 2;
    // pre-swizzled global k-segment: involution seg ^= (srow>>1)&3
    const int sseg = ((t & 3) ^ ((srow >> 1) & 3)) * 8;     // u16 elems
    const u16* Ap = A + (size_t)(row0 + srow) * lda + sseg;
    const u16* Bp = Bt + (size_t)(col0 + srow) * ldb + sseg;
    const size_t lstep = (size_t)64 * lda, bstep = (size_t)64 * ldb;

    auto stage = [&](int buf, int k0) {
        #pragma unroll
        for (int i = 0; i < BM / 64; i++)
            gl_lds16(Ap + i * lstep + k0, &As[buf][i * 2048 + t * 8]);
        #pragma unroll
        for (int i = 0; i < 2; i++)
            gl_lds16(Bp + i * bstep + k0, &Bs[buf][i * 2048 + t * 8]);
    };

    f32x4 acc[4][NR];
    #pragma unroll
    for (int m = 0; m < 4; m++)
        #pragma unroll
        for (int n = 0; n < NR; n++) acc[m][n] = (f32x4){0.f, 0.f, 0.f, 0.f};

    const int nt = K >> 5;
    stage(0, 0);
    stage(1, 32);

    for (int kt = 0; kt < nt; ++kt) {
        if (kt + 1 < nt) {
            if constexpr (BM == 128) asm volatile("s_waitcnt vmcnt(4)" ::: "memory");
            else                     asm volatile("s_waitcnt vmcnt(3)" ::: "memory");
        } else {
            asm volatile("s_waitcnt vmcnt(0)" ::: "memory");
        }
        __builtin_amdgcn_s_barrier();
        __builtin_amdgcn_sched_barrier(0);
        if (kt + 2 < nt) stage((kt + 2) % 3, (kt + 2) * 32);
        const int cur = kt % 3;
        bf16x8 af[4], bfr[NR];
        #pragma unroll
        for (int m = 0; m < 4; m++) {
            const int R = wr + m * 16 + fr;
            af[m] = *(const bf16x8*)&As[cur][R * 32 + ((fg ^ ((R >> 1) & 3)) * 8)];
        }
        #pragma unroll
        for (int n = 0; n < NR; n++) {
            const int R = wc + n * 16 + fr;
            bfr[n] = *(const bf16x8*)&Bs[cur][R * 32 + ((fg ^ ((R >> 1) & 3)) * 8)];
        }
        __builtin_amdgcn_s_setprio(1);
        #pragma unroll
        for (int m = 0; m < 4; m++)
            #pragma unroll
            for (int n = 0; n < NR; n++)
                acc[m][n] = __builtin_amdgcn_mfma_f32_16x16x32_bf16(af[m], bfr[n], acc[m][n], 0, 0, 0);
        __builtin_amdgcn_s_setprio(0);
    }
    #pragma unroll
    for (int m = 0; m < 4; m++) {
        #pragma unroll
        for (int n = 0; n < NR; n++) {
            const int col = col0 + wc + n * 16 + fr;
            const float bb = bias[col];
            #pragma unroll
            for (int r = 0; r < 4; r++) {
                const size_t row = row0 + wr + m * 16 + fg * 4 + r;
                float v = acc[m][n][r] + bb;
                if (EPI == 0) {
                    Cb[row * ldc + col] = f2b(v);
                } else if (EPI == 1) {
                    Cf[row * ldc + col] = v + resid[row * ldc + col];
                } else if (EPI == 2) {
                    Cb[row * ldc + col] = f2b(gelu_fast(v));
                } else if (EPI == 3) {
                    Cf[row * ldc + col] = v;
                } else if (EPI == 5) {
                    const int fi = fidx[row], ti = tidx[row];
                    Cf[row * ldc + col] = v + pf[(size_t)fi * DD + col] + pt[(size_t)ti * DD + col];
                }
            }
        }
    }
}

// ---------------- block-diagonal flash attention (no 1/sqrt(d) scaling) ----------------
// Double-buffered K/V LDS, single barrier per j-tile; Q staged through K-buf1.
__global__ __launch_bounds__(256) void k_attn(
    const u16* __restrict__ qkv,
    const int* __restrict__ sid, const unsigned char* __restrict__ pad,
    const int2* __restrict__ qr,
    u16* __restrict__ outb)
{
    // LDS pool (u16 units): K0[4608] K1[4608] V0[4640] V1[4640] Ps[4608]  (~46.2 KB)
    __shared__ __align__(16) u16 pool[2 * 4608 + 2 * 4640 + 4608];
    u16* const K0  = pool;
    u16* const K1  = pool + 4608;
    u16* const V0  = pool + 9216;
    u16* const V1  = pool + 9216 + 4640;
    u16* const PsB = pool + 9216 + 9280;
    __shared__ int sidq[64];
    __shared__ int sidj[2][64];
    __shared__ int padj[2][64];
    const int b = blockIdx.z, h = blockIdx.y, qt = blockIdx.x;
    const int i0 = qt * 64;
    const int t = threadIdx.x, w = t >> 6, lane = t & 63;
    const int fr = lane & 15, fg = lane >> 4;
    const int srow = t >> 2, sseg = (t & 3) * 16;
    const int goff = (sseg >> 4) << 3;           // V swizzle offset, constant per thread
    const size_t tokbase = (size_t)b * NN;
    const u16* qbase = qkv + (tokbase + i0) * 2304 + h * 64;
    // stage Q via K1 region
    *(uint4*)&K1[srow * 72 + sseg]     = *(const uint4*)(qbase + (size_t)srow * 2304 + sseg);
    *(uint4*)&K1[srow * 72 + sseg + 8] = *(const uint4*)(qbase + (size_t)srow * 2304 + sseg + 8);
    if (t < 64) sidq[t] = sid[tokbase + i0 + t];
    __syncthreads();
    const bf16x8 qf0 = *(const bf16x8*)&K1[(w * 16 + fr) * 72 + fg * 8];
    const bf16x8 qf1 = *(const bf16x8*)&K1[(w * 16 + fr) * 72 + 32 + fg * 8];
    const int myrow = w * 16 + fg * 4;
    float m_run[4], l_run[4];
    f32x4 oacc[4];
    #pragma unroll
    for (int r = 0; r < 4; r++) { m_run[r] = -1e30f; l_run[r] = 0.f; }
    #pragma unroll
    for (int n = 0; n < 4; n++) oacc[n] = (f32x4){0.f, 0.f, 0.f, 0.f};
    const int2 rg = qr[b * 16 + qt];
    const u16* kbase = qkv + tokbase * 2304 + 768 + h * 64;
    const u16* vbase = qkv + tokbase * 2304 + 1536 + h * 64;
    const int jstart = rg.x & ~63;
    const int ntiles = (rg.y - jstart + 63) >> 6;

    // reg prefetch state
    uint4 rk0, rk1, rv0, rv1;
    int rsid = 0, rpad = 0;
    auto load_tile = [&](int tile) {
        const size_t ro = (size_t)(jstart + tile * 64 + srow) * 2304;
        rk0 = *(const uint4*)(kbase + ro + sseg);
        rk1 = *(const uint4*)(kbase + ro + sseg + 8);
        rv0 = *(const uint4*)(vbase + ro + sseg);
        rv1 = *(const uint4*)(vbase + ro + sseg + 8);
        if (t < 64) { rsid = sid[tokbase + jstart + tile * 64 + t]; rpad = pad[tokbase + jstart + tile * 64 + t]; }
    };
    auto write_tile = [&](u16* kb, u16* vb, int slot) {
        *(uint4*)&kb[srow * 72 + sseg]     = rk0;
        *(uint4*)&kb[srow * 72 + sseg + 8] = rk1;
        u16 tmp[16];
        *(uint4*)&tmp[0] = rv0;
        *(uint4*)&tmp[8] = rv1;
        #pragma unroll
        for (int e = 0; e < 16; e++)
            vb[(sseg + e) * 72 + goff + srow] = tmp[e];
        if (t < 64) { sidj[slot][t] = rsid; padj[slot][t] = rpad; }
    };

    // prologue: tile0 -> buf0 (K0/V0: no overlap with Q in K1); tile1 -> regs
    load_tile(0);
    write_tile(K0, V0, 0);
    if (ntiles > 1) load_tile(1);
    __syncthreads();   // Q-frag reads done + tile0 visible

    for (int tt = 0; tt < ntiles; ++tt) {
        const int cb = tt & 1;
        u16* const kb = cb ? K1 : K0;
        u16* const vb = cb ? V1 : V0;
        if (tt + 1 < ntiles) {
            write_tile(cb ? K0 : K1, cb ? V0 : V1, cb ^ 1);
            if (tt + 2 < ntiles) load_tile(tt + 2);
        }
        // S = Q K^T  (16 q-rows per wave x 64 j)
        f32x4 s[4];
        __builtin_amdgcn_s_setprio(1);
        #pragma unroll
        for (int nj = 0; nj < 4; nj++) {
            bf16x8 kf0 = *(const bf16x8*)&kb[(nj * 16 + fr) * 72 + fg * 8];
            bf16x8 kf1 = *(const bf16x8*)&kb[(nj * 16 + fr) * 72 + 32 + fg * 8];
            f32x4 a = (f32x4){0.f, 0.f, 0.f, 0.f};
            a = __builtin_amdgcn_mfma_f32_16x16x32_bf16(qf0, kf0, a, 0, 0, 0);
            a = __builtin_amdgcn_mfma_f32_16x16x32_bf16(qf1, kf1, a, 0, 0, 0);
            s[nj] = a;
        }
        __builtin_amdgcn_s_setprio(0);
        // mask
        #pragma unroll
        for (int nj = 0; nj < 4; nj++) {
            const int jj = nj * 16 + fr;
            const int sj = sidj[cb][jj];
            const int pd = padj[cb][jj];
            #pragma unroll
            for (int r = 0; r < 4; r++) {
                const bool ok = pd && (sj == sidq[myrow + r]);
                s[nj][r] = ok ? s[nj][r] : -3e38f;
            }
        }
        // online softmax (rows live on 16-lane groups)
        float mnew[4], scale[4];
        #pragma unroll
        for (int r = 0; r < 4; r++) {
            float mx = fmaxf(fmaxf(s[0][r], s[1][r]), fmaxf(s[2][r], s[3][r]));
            #pragma unroll
            for (int o = 1; o < 16; o <<= 1) mx = fmaxf(mx, __shfl_xor(mx, o));
            mnew[r] = fmaxf(m_run[r], mx);
            scale[r] = __expf(m_run[r] - mnew[r]);
            m_run[r] = mnew[r];
        }
        #pragma unroll
        for (int r = 0; r < 4; r++) {
            float rs = 0.f;
            #pragma unroll
            for (int nj = 0; nj < 4; nj++) {
                float pv = __expf(s[nj][r] - mnew[r]);
                rs += pv;
                PsB[(w * 16 + fg * 4 + r) * 72 + nj * 16 + fr] = f2b(pv);
            }
            #pragma unroll
            for (int o = 1; o < 16; o <<= 1) rs += __shfl_xor(rs, o);
            l_run[r] = l_run[r] * scale[r] + rs;
        }
        #pragma unroll
        for (int n = 0; n < 4; n++)
            #pragma unroll
            for (int r = 0; r < 4; r++) oacc[n][r] *= scale[r];
        // O += P V   (P via per-wave LDS relayout; same-wave DS ordering is program order)
        bf16x8 pa0 = *(const bf16x8*)&PsB[(w * 16 + fr) * 72 + fg * 8];
        bf16x8 pa1 = *(const bf16x8*)&PsB[(w * 16 + fr) * 72 + 32 + fg * 8];
        __builtin_amdgcn_s_setprio(1);
        #pragma unroll
        for (int nd = 0; nd < 4; nd++) {
            bf16x8 vf0 = *(const bf16x8*)&vb[(nd * 16 + fr) * 72 + nd * 8 + fg * 8];
            bf16x8 vf1 = *(const bf16x8*)&vb[(nd * 16 + fr) * 72 + nd * 8 + 32 + fg * 8];
            oacc[nd] = __builtin_amdgcn_mfma_f32_16x16x32_bf16(pa0, vf0, oacc[nd], 0, 0, 0);
            oacc[nd] = __builtin_amdgcn_mfma_f32_16x16x32_bf16(pa1, vf1, oacc[nd], 0, 0, 0);
        }
        __builtin_amdgcn_s_setprio(0);
        __syncthreads();   // readers of buf[tt] done; writes of buf[tt+1] visible
    }
    float inv[4];
    #pragma unroll
    for (int r = 0; r < 4; r++) inv[r] = 1.f / l_run[r];
    #pragma unroll
    for (int nd = 0; nd < 4; nd++)
        #pragma unroll
        for (int r = 0; r < 4; r++)
            outb[(tokbase + i0 + myrow + r) * DD + h * 64 + nd * 16 + fr] = f2b(oacc[nd][r] * inv[r]);
}

// ---------------- pool query vector: qv[c] = pool_q . pool_Wq[:,c] + pool_bq[c] ----------------
__global__ __launch_bounds__(64) void k_qvec(const float* __restrict__ pq, const float* __restrict__ Wq,
                                             const float* __restrict__ bq, float* __restrict__ qv) {
    int c = blockIdx.x;
    int l = threadIdx.x;
    float s = 0.f;
    #pragma unroll
    for (int d = l; d < DD; d += 64) s += pq[d] * Wq[(size_t)d * DD + c];
    #pragma unroll
    for (int o = 32; o; o >>= 1) s += __shfl_xor(s, o);
    if (l == 0) qv[c] = s + bq[c];
}

// ---------------- attention pooling: one block per (b, m, h) ----------------
__global__ __launch_bounds__(256) void k_pool_attn(
    const float* __restrict__ qv, const u16* __restrict__ kv,
    const unsigned char* __restrict__ pad, const int2* __restrict__ pr,
    float* __restrict__ outp)
{
    const int idx = blockIdx.x;                 // ((b*8+m)*12+h)
    const int h = idx % HHH, bm = idx / HHH;
    const int b = bm >> 3, m = bm & 7;
    const int2 rg = pr[b * MMM + m];
    const int lo = rg.x, cnt = rg.y - rg.x;
    __shared__ float sc[NN];
    __shared__ float qsh[64];
    __shared__ float rbuf[4];
    __shared__ float vacc[4][64];
    if (threadIdx.x < 64) qsh[threadIdx.x] = qv[h * 64 + threadIdx.x];
    __syncthreads();
    // scores (vectorized 16B K loads)
    for (int j = threadIdx.x; j < cnt; j += 256) {
        const u16* krow = kv + (size_t)(b * NN + lo + j) * 1536 + h * 64;
        float s = 0.f;
        #pragma unroll
        for (int dv = 0; dv < 8; dv++) {
            bf16x8 k8 = *(const bf16x8*)(krow + dv * 8);
            #pragma unroll
            for (int e = 0; e < 8; e++) s += qsh[dv * 8 + e] * b2f((u16)k8[e]);
        }
        sc[j] = pad[b * NN + lo + j] ? s : -3e38f;
    }
    __syncthreads();
    float mx = -3e38f;
    for (int j = threadIdx.x; j < cnt; j += 256) mx = fmaxf(mx, sc[j]);
    #pragma unroll
    for (int o = 32; o; o >>= 1) mx = fmaxf(mx, __shfl_xor(mx, o));
    if ((threadIdx.x & 63) == 0) rbuf[threadIdx.x >> 6] = mx;
    __syncthreads();
    mx = fmaxf(fmaxf(rbuf[0], rbuf[1]), fmaxf(rbuf[2], rbuf[3]));
    __syncthreads();
    float sm = 0.f;
    for (int j = threadIdx.x; j < cnt; j += 256) { float p = __expf(sc[j] - mx); sc[j] = p; sm += p; }
    #pragma unroll
    for (int o = 32; o; o >>= 1) sm += __shfl_xor(sm, o);
    if ((threadIdx.x & 63) == 0) rbuf[threadIdx.x >> 6] = sm;
    __syncthreads();
    sm = rbuf[0] + rbuf[1] + rbuf[2] + rbuf[3];
    const float inv = 1.f / sm;
    {
        const int d = threadIdx.x & 63, g = threadIdx.x >> 6;
        float acc = 0.f;
        for (int j = g; j < cnt; j += 4)
            acc += sc[j] * b2f(kv[(size_t)(b * NN + lo + j) * 1536 + 768 + h * 64 + d]);
        vacc[g][d] = acc;
        __syncthreads();
        if (g == 0)
            outp[(size_t)(b * MMM + m) * DD + h * 64 + d] =
                (vacc[0][d] + vacc[1][d] + vacc[2][d] + vacc[3][d]) * inv;
    }
}

// ---------------- small f32 GEMM: out[32][N] = A[32][768] @ W[768][N] + bias ----------------
__global__ __launch_bounds__(256) void k_small_mm(const float* __restrict__ A, const float* __restrict__ W,
                                                  const float* __restrict__ bias, float* __restrict__ out,
                                                  int N, int Kd) {
    const int row = blockIdx.y;
    const int cl = threadIdx.x & 63, kg = threadIdx.x >> 6;
    const int c = blockIdx.x * 64 + cl;
    const int cload = (c < N) ? c : (N - 1);
    __shared__ float As[DD];
    __shared__ float red[4][64];
    for (int d = threadIdx.x; d < Kd; d += 256) As[d] = A[(size_t)row * Kd + d];
    __syncthreads();
    const int kper = Kd >> 2;
    const int kbase = kg * kper;
    float s = 0.f;
    const float* w = W + (size_t)kbase * N + cload;
    #pragma unroll 4
    for (int i = 0; i < kper; i++) s += As[kbase + i] * w[(size_t)i * N];
    red[kg][cl] = s;
    __syncthreads();
    if (kg == 0 && c < N)
        out[(size_t)row * N + c] = red[0][cl] + red[1][cl] + red[2][cl] + red[3][cl] + bias[c];
}

// =======================================================================
extern "C" void kernel_launch(void* const* d_in, const int* in_sizes, int n_in,
                              void* d_out, int out_size, void* d_ws, size_t ws_size,
                              hipStream_t stream) {
    const float* patches   = (const float*)d_in[0];
    const int*   sample_ids= (const int*)d_in[1];
    const void*  key_pad_raw = (const void*)d_in[2];   // bool: byte OR int32 — normalized below
    const int*   freq_idx  = (const int*)d_in[3];
    const int*   time_idx  = (const int*)d_in[4];
    const float* patch_W   = (const float*)d_in[5];
    const float* patch_b   = (const float*)d_in[6];
    const float* pos_f     = (const float*)d_in[7];
    const float* pos_t     = (const float*)d_in[8];
    const float* ln1_g     = (const float*)d_in[9];
    const float* ln1_b     = (const float*)d_in[10];
    const float* Wq        = (const float*)d_in[11];
    const float* bq        = (const float*)d_in[12];
    const float* Wkv       = (const float*)d_in[13];
    const float* bkv       = (const float*)d_in[14];
    const float* Wo        = (const float*)d_in[15];
    const float* bo        = (const float*)d_in[16];
    const float* ln2_g     = (const float*)d_in[17];
    const float* ln2_b     = (const float*)d_in[18];
    const float* W1        = (const float*)d_in[19];
    const float* b1        = (const float*)d_in[20];
    const float* W2        = (const float*)d_in[21];
    const float* b2        = (const float*)d_in[22];
    const float* norm_g    = (const float*)d_in[23];
    const float* norm_b    = (const float*)d_in[24];
    const float* pool_q    = (const float*)d_in[25];
    const float* pool_Wq   = (const float*)d_in[26];
    const float* pool_bq   = (const float*)d_in[27];
    const float* pool_Wkv  = (const float*)d_in[28];
    const float* pool_bkv  = (const float*)d_in[29];
    const float* pool_Wo   = (const float*)d_in[30];
    const float* pool_bo   = (const float*)d_in[31];
    const float* mln_g     = (const float*)d_in[32];
    const float* mln_b     = (const float*)d_in[33];
    const float* head_W    = (const float*)d_in[34];
    const float* head_b    = (const float*)d_in[35];
    float* outp = (float*)d_out;
    (void)in_sizes; (void)n_in; (void)out_size; (void)ws_size;

    char* ws = (char*)d_ws;
    size_t off = 0;
    auto alloc = [&](size_t bytes) -> void* {
        void* p = (void*)(ws + off);
        off += (bytes + 255) & ~(size_t)255;
        return p;
    };
    // persistent: bf16 transposed weights (~165 MB)
    u16* WqkvT    = (u16*)alloc((size_t)LLL * 2304 * 768 * 2);
    u16* WoT      = (u16*)alloc((size_t)LLL * 768 * 768 * 2);
    u16* W1T      = (u16*)alloc((size_t)LLL * 3072 * 768 * 2);
    u16* W2T      = (u16*)alloc((size_t)LLL * 768 * 3072 * 2);
    u16* patchWT  = (u16*)alloc((size_t)768 * 256 * 2);
    u16* poolWkvT = (u16*)alloc((size_t)1536 * 768 * 2);
    float* bqkv   = (float*)alloc((size_t)LLL * 2304 * 4);
    unsigned char* pad_u8 = (unsigned char*)alloc(BB * NN);
    // activations (~66 MB, with aliasing)
    float* x      = (float*)alloc((size_t)4096 * 768 * 4);
    u16* hbuf     = (u16*)alloc((size_t)4096 * 768 * 2);
    u16* qkvb     = (u16*)alloc((size_t)4096 * 2304 * 2);
    u16* attno    = (u16*)alloc((size_t)4096 * 768 * 2);
    u16* mid      = (u16*)alloc((size_t)4096 * 3072 * 2);
    u16* patch_bf = mid;     // alias: patch_bf (4096x256) dead before first W1 GEMM
    u16* xn       = attno;   // alias: xn written after last attno read
    u16* poolkv   = qkvb;    // alias: poolkv written after last qkvb read
    float* qvec   = (float*)alloc(768 * 4);
    float* pooled_pre = (float*)alloc(32 * 768 * 4);
    float* pooled2    = (float*)alloc(32 * 768 * 4);
    float* mlnout     = (float*)alloc(32 * 768 * 4);
    int2* qr = (int2*)alloc(4 * 16 * sizeof(int2));
    int2* pr = (int2*)alloc(4 * 8 * sizeof(int2));

    // ---- input prep ----
    k_pad_norm<<<1, 1024, 0, stream>>>(key_pad_raw, pad_u8, BB * NN);
    k_transpose_cvt<<<dim3(24, 12, LLL), 256, 0, stream>>>(Wq, WqkvT, 768, 768, (long)768 * 768, (long)2304 * 768);
    k_transpose_cvt<<<dim3(48, 12, LLL), 256, 0, stream>>>(Wkv, WqkvT + (size_t)768 * 768, 768, 1536, (long)768 * 1536, (long)2304 * 768);
    k_transpose_cvt<<<dim3(24, 12, LLL), 256, 0, stream>>>(Wo, WoT, 768, 768, (long)768 * 768, (long)768 * 768);
    k_transpose_cvt<<<dim3(96, 12, LLL), 256, 0, stream>>>(W1, W1T, 768, 3072, (long)768 * 3072, (long)3072 * 768);
    k_transpose_cvt<<<dim3(24, 48, LLL), 256, 0, stream>>>(W2, W2T, 3072, 768, (long)3072 * 768, (long)768 * 3072);
    k_transpose_cvt<<<dim3(24, 4, 1), 256, 0, stream>>>(patch_W, patchWT, 256, 768, 0, 0);
    k_transpose_cvt<<<dim3(48, 12, 1), 256, 0, stream>>>(pool_Wkv, poolWkvT, 768, 1536, 0, 0);
    k_cvt<<<1024, 256, 0, stream>>>(patches, patch_bf, 4096 * 256 / 4);
    k_bias_pack<<<(LLL * 2304 + 255) / 256, 256, 0, stream>>>(bq, bkv, bqkv);
    k_ranges<<<4, 64, 0, stream>>>(sample_ids, qr, pr);

    // ---- embed + positional (fused epilogue) ----
    k_gemm<5, 64><<<dim3(6, 64), 256, 0, stream>>>(patch_bf, 256, patchWT, 256, patch_b, x, nullptr, nullptr,
                                                   768, 256, freq_idx, time_idx, pos_f, pos_t);

    // ---- transformer layers ----
    for (int l = 0; l < LLL; l++) {
        k_ln<u16><<<1024, 256, 0, stream>>>(x, ln1_g + l * 768, ln1_b + l * 768, hbuf);
        k_gemm<0, 128><<<dim3(18, 32), 256, 0, stream>>>(hbuf, 768, WqkvT + (size_t)l * 2304 * 768, 768,
                                                         bqkv + l * 2304, nullptr, qkvb, nullptr, 2304, 768);
        k_attn<<<dim3(16, 12, 4), 256, 0, stream>>>(qkvb, sample_ids, pad_u8, qr, attno);
        k_gemm<1, 64><<<dim3(6, 64), 256, 0, stream>>>(attno, 768, WoT + (size_t)l * 768 * 768, 768,
                                                       bo + l * 768, x, nullptr, x, 768, 768);
        k_ln<u16><<<1024, 256, 0, stream>>>(x, ln2_g + l * 768, ln2_b + l * 768, hbuf);
        k_gemm<2, 128><<<dim3(24, 32), 256, 0, stream>>>(hbuf, 768, W1T + (size_t)l * 3072 * 768, 768,
                                                         b1 + l * 3072, nullptr, mid, nullptr, 3072, 768);
        k_gemm<1, 64><<<dim3(6, 64), 256, 0, stream>>>(mid, 3072, W2T + (size_t)l * 768 * 3072, 3072,
                                                       b2 + l * 768, x, nullptr, x, 768, 3072);
    }

    // ---- final norm + pooling + head ----
    k_ln<u16><<<1024, 256, 0, stream>>>(x, norm_g, norm_b, xn);
    k_gemm<0, 128><<<dim3(12, 32), 256, 0, stream>>>(xn, 768, poolWkvT, 768, pool_bkv, nullptr, poolkv, nullptr, 1536, 768);
    k_qvec<<<768, 64, 0, stream>>>(pool_q, pool_Wq, pool_bq, qvec);
    k_pool_attn<<<BB * MMM * HHH, 256, 0, stream>>>(qvec, poolkv, pad_u8, pr, pooled_pre);
    k_small_mm<<<dim3(12, 32), 256, 0, stream>>>(pooled_pre, pool_Wo, pool_bo, pooled2, 768, 768);
    k_ln<float><<<8, 256, 0, stream>>>(pooled2, mln_g, mln_b, mlnout);
    k_small_mm<<<dim3(9, 32), 256, 0, stream>>>(mlnout, head_W, head_b, outp, 527, 768);
}